// Round 3
// baseline (1504.252 us; speedup 1.0000x reference)
//
#include <hip/hip_runtime.h>

// NNPredictor: edge MLP with BN folded into weights.
// R3: software-pipelined k_L1/k_L2 — prefetch next-chunk gathers/A-frags,
//     double-buffered LDS tile, single barrier per iteration, 16B gathers.

#define N_EDGES 800000
#define N_NODES 50000

typedef __attribute__((ext_vector_type(8))) short bf8_t;
typedef __attribute__((ext_vector_type(4))) float f4_t;

__device__ __forceinline__ unsigned short f2bf(float f) {
    unsigned int u = __builtin_bit_cast(unsigned int, f);
    u += 0x7FFFu + ((u >> 16) & 1u);
    return (unsigned short)(u >> 16);
}
__device__ __forceinline__ float bf2f(unsigned short s) {
    unsigned int u = ((unsigned int)s) << 16;
    return __builtin_bit_cast(float, u);
}
__device__ __forceinline__ bf8_t cvt8(f4_t x, f4_t y) {
    bf8_t r;
    r[0] = (short)f2bf(x[0]); r[1] = (short)f2bf(x[1]);
    r[2] = (short)f2bf(x[2]); r[3] = (short)f2bf(x[3]);
    r[4] = (short)f2bf(y[0]); r[5] = (short)f2bf(y[1]);
    r[6] = (short)f2bf(y[2]); r[7] = (short)f2bf(y[3]);
    return r;
}

__global__ __launch_bounds__(256) void k_hist(const int* __restrict__ src, const int* __restrict__ dst,
                                              int* __restrict__ cs, int* __restrict__ cd) {
    int i = blockIdx.x * 256 + threadIdx.x;
    if (i < N_EDGES) {
        atomicAdd(&cs[src[i]], 1);
        atomicAdd(&cd[dst[i]], 1);
    }
}

__global__ __launch_bounds__(256) void k_estats(const float* __restrict__ e,
                                                float* __restrict__ sum, float* __restrict__ sq) {
    const int tid = threadIdx.x;
    const int x = tid & 15, r = tid >> 4;
    f4_t s = {0.f, 0.f, 0.f, 0.f}, q = {0.f, 0.f, 0.f, 0.f};
    for (size_t i = blockIdx.x * 16 + r; i < N_EDGES; i += (size_t)gridDim.x * 16) {
        f4_t v = *(const f4_t*)(e + i * 64 + x * 4);
        s += v; q += v * v;
    }
    __shared__ float red[128];
    if (tid < 128) red[tid] = 0.f;
    __syncthreads();
#pragma unroll
    for (int j = 0; j < 4; ++j) {
        atomicAdd(&red[x * 4 + j], s[j]);
        atomicAdd(&red[64 + x * 4 + j], q[j]);
    }
    __syncthreads();
    if (tid < 64) atomicAdd(&sum[256 + tid], red[tid]);
    else if (tid < 128) atomicAdd(&sq[256 + tid - 64], red[tid]);
}

__global__ __launch_bounds__(256) void k_hstats(const float* __restrict__ h,
                                                const int* __restrict__ cs, const int* __restrict__ cd,
                                                float* __restrict__ sum, float* __restrict__ sq) {
    const int tid = threadIdx.x;
    const int c = tid & 127, g = tid >> 7;
    float ss = 0.f, qs = 0.f, sd = 0.f, qd = 0.f;
    for (int n = blockIdx.x * 2 + g; n < N_NODES; n += gridDim.x * 2) {
        float v = h[(size_t)n * 128 + c];
        float a = (float)cs[n], b = (float)cd[n];
        ss += a * v; qs += a * v * v;
        sd += b * v; qd += b * v * v;
    }
    __shared__ float red[256];
    red[tid] = ss; __syncthreads();
    if (tid < 128) atomicAdd(&sum[tid], red[tid] + red[tid + 128]);
    __syncthreads();
    red[tid] = qs; __syncthreads();
    if (tid < 128) atomicAdd(&sq[tid], red[tid] + red[tid + 128]);
    __syncthreads();
    red[tid] = sd; __syncthreads();
    if (tid < 128) atomicAdd(&sum[128 + tid], red[tid] + red[tid + 128]);
    __syncthreads();
    red[tid] = qd; __syncthreads();
    if (tid < 128) atomicAdd(&sq[128 + tid], red[tid] + red[tid + 128]);
}

__global__ __launch_bounds__(320) void k_fold0(const float* __restrict__ sum, const float* __restrict__ sq,
        const float* __restrict__ g0, const float* __restrict__ b0,
        float* __restrict__ scale0, float* __restrict__ shift0) {
    int j = threadIdx.x;
    if (j < 320) {
        const float invE = 1.f / (float)N_EDGES;
        float mu = sum[j] * invE;
        float var = sq[j] * invE - mu * mu;
        float sc = g0[j] * rsqrtf(var + 1e-5f);
        scale0[j] = sc;
        shift0[j] = b0[j] - mu * sc;
    }
}

__global__ __launch_bounds__(320) void k_foldW1(const float* __restrict__ W1, const float* __restrict__ b1,
        const float* __restrict__ scale0, const float* __restrict__ shift0,
        unsigned short* __restrict__ W1s, unsigned short* __restrict__ W1d,
        unsigned short* __restrict__ W1e, float* __restrict__ b1p) {
    __shared__ float sc[320], sh[320];
    const int tid = threadIdx.x;
    if (tid < 320) { sc[tid] = scale0[tid]; sh[tid] = shift0[tid]; }
    __syncthreads();
    if (tid < 256) {
        float acc = b1[tid];
        const float* wr = W1 + (size_t)tid * 320;
        for (int j = 0; j < 320; ++j) {
            float wv = wr[j];
            acc += wv * sh[j];
            unsigned short wb = f2bf(wv * sc[j]);
            if (j < 128) W1s[tid * 128 + j] = wb;
            else if (j < 256) W1d[tid * 128 + (j - 128)] = wb;
            else W1e[tid * 64 + (j - 256)] = wb;
        }
        b1p[tid] = acc;
    }
}

// P = h @ W'^T : M=50000 (256/block), N=256, K=128.
__global__ __launch_bounds__(256) void k_P(const float* __restrict__ h,
        const unsigned short* __restrict__ W1s, const unsigned short* __restrict__ W1d,
        unsigned short* __restrict__ Ps, unsigned short* __restrict__ Pd) {
    __shared__ unsigned short tile[16 * 264];
    const int tid = threadIdx.x;
    const int w = tid >> 6, lane = tid & 63, quad = lane >> 4, l15 = lane & 15;
    const unsigned short* W = blockIdx.y ? W1d : W1s;
    unsigned short* P = blockIdx.y ? Pd : Ps;
    const size_t base = (size_t)blockIdx.x * 256;
    bf8_t bfr[4][4];
#pragma unroll
    for (int j = 0; j < 4; ++j) {
        const unsigned short* wp = W + (size_t)((w * 4 + j) * 16 + l15) * 128 + quad * 8;
#pragma unroll
        for (int ks = 0; ks < 4; ++ks) bfr[j][ks] = *(const bf8_t*)(wp + ks * 32);
    }
    const int erow = tid >> 4, ex = tid & 15;
    for (int mc = 0; mc < 16; ++mc) {
        const size_t row0 = base + mc * 16;
        size_t ar = row0 + l15; if (ar >= N_NODES) ar = N_NODES - 1;
        const float* hp = h + ar * 128 + quad * 8;
        bf8_t af[4];
#pragma unroll
        for (int ks = 0; ks < 4; ++ks)
            af[ks] = cvt8(*(const f4_t*)(hp + ks * 32), *(const f4_t*)(hp + ks * 32 + 4));
#pragma unroll
        for (int j = 0; j < 4; ++j) {
            f4_t t = {0.f, 0.f, 0.f, 0.f};
#pragma unroll
            for (int ks = 0; ks < 4; ++ks)
                t = __builtin_amdgcn_mfma_f32_16x16x32_bf16(af[ks], bfr[j][ks], t, 0, 0, 0);
#pragma unroll
            for (int r = 0; r < 4; ++r)
                tile[(quad * 4 + r) * 264 + (w * 4 + j) * 16 + l15] = f2bf(t[r]);
        }
        __syncthreads();
        const size_t orow = row0 + erow;
        if (orow < N_NODES) {
            uint4 v0 = *(const uint4*)(tile + erow * 264 + ex * 16);
            uint4 v1 = *(const uint4*)(tile + erow * 264 + ex * 16 + 8);
            *(uint4*)(P + orow * 256 + ex * 16) = v0;
            *(uint4*)(P + orow * 256 + ex * 16 + 8) = v1;
        }
        __syncthreads();
    }
}

// a1 = ReLU(e@W1e' + Ps[src] + Pd[dst] + b1'); BN1 stats.
// Pipelined: prefetch e + gathers for chunk mc+1 during chunk mc; dbuf tile, 1 barrier/iter.
__global__ __launch_bounds__(256, 2) void k_L1(const float* __restrict__ e,
        const int* __restrict__ src, const int* __restrict__ dst,
        const unsigned short* __restrict__ Ps, const unsigned short* __restrict__ Pd,
        const unsigned short* __restrict__ W1e, const float* __restrict__ b1p,
        unsigned short* __restrict__ a1, float* __restrict__ slots) {
    __shared__ float tile[2][16 * 260];
    __shared__ float bn[512];
    __shared__ int sIdx[256], dIdx[256];
    const int tid = threadIdx.x;
    const int w = tid >> 6, lane = tid & 63, quad = lane >> 4, l15 = lane & 15;
    const size_t base = (size_t)blockIdx.x * 256;
    bn[tid] = 0.f; bn[256 + tid] = 0.f;
    sIdx[tid] = src[base + tid];
    dIdx[tid] = dst[base + tid];
    bf8_t bfr[4][2];
#pragma unroll
    for (int j = 0; j < 4; ++j) {
        const unsigned short* wp = W1e + (size_t)((w * 4 + j) * 16 + l15) * 64 + quad * 8;
#pragma unroll
        for (int ks = 0; ks < 2; ++ks) bfr[j][ks] = *(const bf8_t*)(wp + ks * 32);
    }
    const int erow = tid >> 4, ex = tid & 15;
    float bias[2][8], sreg[2][8], qreg[2][8];
#pragma unroll
    for (int i = 0; i < 2; ++i) {
        f4_t ba = *(const f4_t*)(b1p + ex * 8 + 128 * i);
        f4_t bb = *(const f4_t*)(b1p + ex * 8 + 4 + 128 * i);
#pragma unroll
        for (int j = 0; j < 4; ++j) {
            bias[i][j] = ba[j]; bias[i][4 + j] = bb[j];
            sreg[i][j] = 0.f; sreg[i][4 + j] = 0.f;
            qreg[i][j] = 0.f; qreg[i][4 + j] = 0.f;
        }
    }
    __syncthreads();  // publish sIdx/dIdx
    f4_t eb[2][4];
    uint4 gs[2][2], gd[2][2];
    {   // prologue: loads for chunk 0
        const float* ep = e + (base + l15) * 64 + quad * 8;
        eb[0][0] = *(const f4_t*)(ep);      eb[0][1] = *(const f4_t*)(ep + 4);
        eb[0][2] = *(const f4_t*)(ep + 32); eb[0][3] = *(const f4_t*)(ep + 36);
        const size_t sr = (size_t)sIdx[erow] * 256, dr = (size_t)dIdx[erow] * 256;
#pragma unroll
        for (int i = 0; i < 2; ++i) {
            gs[0][i] = *(const uint4*)(Ps + sr + ex * 8 + 128 * i);
            gd[0][i] = *(const uint4*)(Pd + dr + ex * 8 + 128 * i);
        }
    }
#pragma unroll
    for (int mc = 0; mc < 16; ++mc) {
        const int buf = mc & 1;
        bf8_t a0 = cvt8(eb[buf][0], eb[buf][1]);
        bf8_t a1f = cvt8(eb[buf][2], eb[buf][3]);
#pragma unroll
        for (int j = 0; j < 4; ++j) {
            f4_t t = {0.f, 0.f, 0.f, 0.f};
            t = __builtin_amdgcn_mfma_f32_16x16x32_bf16(a0, bfr[j][0], t, 0, 0, 0);
            t = __builtin_amdgcn_mfma_f32_16x16x32_bf16(a1f, bfr[j][1], t, 0, 0, 0);
#pragma unroll
            for (int r = 0; r < 4; ++r)
                tile[buf][(quad * 4 + r) * 260 + (w * 4 + j) * 16 + l15] = t[r];
        }
        if (mc < 15) {  // prefetch chunk mc+1
            const float* ep = e + (base + (mc + 1) * 16 + l15) * 64 + quad * 8;
            eb[buf ^ 1][0] = *(const f4_t*)(ep);      eb[buf ^ 1][1] = *(const f4_t*)(ep + 4);
            eb[buf ^ 1][2] = *(const f4_t*)(ep + 32); eb[buf ^ 1][3] = *(const f4_t*)(ep + 36);
            const size_t sr = (size_t)sIdx[(mc + 1) * 16 + erow] * 256;
            const size_t dr = (size_t)dIdx[(mc + 1) * 16 + erow] * 256;
#pragma unroll
            for (int i = 0; i < 2; ++i) {
                gs[buf ^ 1][i] = *(const uint4*)(Ps + sr + ex * 8 + 128 * i);
                gd[buf ^ 1][i] = *(const uint4*)(Pd + dr + ex * 8 + 128 * i);
            }
        }
        __syncthreads();
        unsigned short* op = a1 + (base + mc * 16 + erow) * 256;
#pragma unroll
        for (int i = 0; i < 2; ++i) {
            const int c0 = ex * 8 + 128 * i;
            f4_t g0 = *(const f4_t*)(tile[buf] + erow * 260 + c0);
            f4_t g1 = *(const f4_t*)(tile[buf] + erow * 260 + c0 + 4);
            const unsigned short* ss = (const unsigned short*)&gs[buf][i];
            const unsigned short* dd = (const unsigned short*)&gd[buf][i];
            unsigned short ov[8];
#pragma unroll
            for (int j = 0; j < 8; ++j) {
                float v = (j < 4 ? g0[j & 3] : g1[j & 3]) + bf2f(ss[j]) + bf2f(dd[j]) + bias[i][j];
                v = fmaxf(v, 0.f);
                ov[j] = f2bf(v);
                sreg[i][j] += v; qreg[i][j] += v * v;
            }
            *(uint4*)(op + c0) = *(const uint4*)ov;
        }
    }
#pragma unroll
    for (int i = 0; i < 2; ++i)
#pragma unroll
        for (int j = 0; j < 8; ++j) {
            const int c = ex * 8 + 128 * i + j;
            atomicAdd(&bn[c], sreg[i][j]);
            atomicAdd(&bn[256 + c], qreg[i][j]);
        }
    __syncthreads();
    float* sl = slots + (size_t)(blockIdx.x & 63) * 512;
    atomicAdd(&sl[tid], bn[tid]);
    atomicAdd(&sl[tid + 256], bn[tid + 256]);
}

__global__ __launch_bounds__(256) void k_fold1(const float* __restrict__ slots,
        const float* __restrict__ g1, const float* __restrict__ b1n,
        const float* __restrict__ W2, const float* __restrict__ b2,
        unsigned short* __restrict__ W2p, float* __restrict__ b2p) {
    __shared__ float sc[256], sh[256];
    const int tid = threadIdx.x;
    float S = 0.f, Q = 0.f;
    for (int s = 0; s < 64; ++s) { S += slots[s * 512 + tid]; Q += slots[s * 512 + 256 + tid]; }
    const float invE = 1.f / (float)N_EDGES;
    float mu = S * invE;
    float var = Q * invE - mu * mu;
    float scl = g1[tid] * rsqrtf(var + 1e-5f);
    sc[tid] = scl; sh[tid] = b1n[tid] - mu * scl;
    __syncthreads();
    if (tid < 128) {
        float acc = b2[tid];
        const float* wr = W2 + (size_t)tid * 256;
        for (int j = 0; j < 256; ++j) {
            float wv = wr[j];
            acc += wv * sh[j];
            W2p[tid * 256 + j] = f2bf(wv * sc[j]);
        }
        b2p[tid] = acc;
    }
}

// a2 = ReLU(a1 @ W2'^T + b2'); BN2 stats. Pipelined like k_L1.
__global__ __launch_bounds__(256, 2) void k_L2(const unsigned short* __restrict__ a1,
        const unsigned short* __restrict__ W2p, const float* __restrict__ b2p,
        unsigned short* __restrict__ a2, float* __restrict__ slots) {
    __shared__ unsigned short tile[2][16 * 136];
    __shared__ float bn[256];
    const int tid = threadIdx.x;
    const int w = tid >> 6, lane = tid & 63, quad = lane >> 4, l15 = lane & 15;
    const size_t base = (size_t)blockIdx.x * 256;
    bn[tid] = 0.f;
    bf8_t bfr[2][8];
#pragma unroll
    for (int j = 0; j < 2; ++j) {
        const unsigned short* wp = W2p + (size_t)((w * 2 + j) * 16 + l15) * 256 + quad * 8;
#pragma unroll
        for (int ks = 0; ks < 8; ++ks) bfr[j][ks] = *(const bf8_t*)(wp + ks * 32);
    }
    const float bias0 = b2p[(w * 2) * 16 + l15];
    const float bias1 = b2p[(w * 2 + 1) * 16 + l15];
    const int erow = tid >> 4, ecol = (tid & 15) * 8;
    float sreg[8], qreg[8];
#pragma unroll
    for (int j = 0; j < 8; ++j) { sreg[j] = 0.f; qreg[j] = 0.f; }
    bf8_t afr[2][8];
    {
        const unsigned short* ap = a1 + (base + l15) * 256 + quad * 8;
#pragma unroll
        for (int ks = 0; ks < 8; ++ks) afr[0][ks] = *(const bf8_t*)(ap + ks * 32);
    }
#pragma unroll
    for (int mc = 0; mc < 16; ++mc) {
        const int buf = mc & 1;
        f4_t acc0 = {0.f, 0.f, 0.f, 0.f}, acc1 = {0.f, 0.f, 0.f, 0.f};
#pragma unroll
        for (int ks = 0; ks < 8; ++ks) {
            acc0 = __builtin_amdgcn_mfma_f32_16x16x32_bf16(afr[buf][ks], bfr[0][ks], acc0, 0, 0, 0);
            acc1 = __builtin_amdgcn_mfma_f32_16x16x32_bf16(afr[buf][ks], bfr[1][ks], acc1, 0, 0, 0);
        }
        if (mc < 15) {
            const unsigned short* ap = a1 + (base + (mc + 1) * 16 + l15) * 256 + quad * 8;
#pragma unroll
            for (int ks = 0; ks < 8; ++ks) afr[buf ^ 1][ks] = *(const bf8_t*)(ap + ks * 32);
        }
#pragma unroll
        for (int r = 0; r < 4; ++r) {
            tile[buf][(quad * 4 + r) * 136 + (w * 2) * 16 + l15] = f2bf(fmaxf(acc0[r] + bias0, 0.f));
            tile[buf][(quad * 4 + r) * 136 + (w * 2 + 1) * 16 + l15] = f2bf(fmaxf(acc1[r] + bias1, 0.f));
        }
        __syncthreads();
        uint4 v = *(const uint4*)(tile[buf] + erow * 136 + ecol);
        *(uint4*)(a2 + (base + mc * 16 + erow) * 128 + ecol) = v;
        const unsigned short* us = (const unsigned short*)&v;
#pragma unroll
        for (int j = 0; j < 8; ++j) { float f = bf2f(us[j]); sreg[j] += f; qreg[j] += f * f; }
    }
#pragma unroll
    for (int j = 0; j < 8; ++j) {
        atomicAdd(&bn[ecol + j], sreg[j]);
        atomicAdd(&bn[128 + ecol + j], qreg[j]);
    }
    __syncthreads();
    atomicAdd(&slots[(size_t)(blockIdx.x & 63) * 256 + tid], bn[tid]);
}

__global__ __launch_bounds__(128) void k_fold2(const float* __restrict__ slots,
        const float* __restrict__ g2, const float* __restrict__ b2n,
        const float* __restrict__ W3, const float* __restrict__ b3,
        float* __restrict__ w3p, float* __restrict__ b3p) {
    __shared__ float red[128];
    const int tid = threadIdx.x;
    float S = 0.f, Q = 0.f;
    for (int s = 0; s < 64; ++s) { S += slots[s * 256 + tid]; Q += slots[s * 256 + 128 + tid]; }
    const float invE = 1.f / (float)N_EDGES;
    float mu = S * invE;
    float var = Q * invE - mu * mu;
    float scl = g2[tid] * rsqrtf(var + 1e-5f);
    float shf = b2n[tid] - mu * scl;
    w3p[tid] = W3[tid] * scl;
    red[tid] = W3[tid] * shf;
    __syncthreads();
    for (int st = 64; st > 0; st >>= 1) {
        if (tid < st) red[tid] += red[tid + st];
        __syncthreads();
    }
    if (tid == 0) b3p[0] = b3[0] + red[0];
}

__global__ __launch_bounds__(256) void k_L3(const unsigned short* __restrict__ a2,
        const float* __restrict__ w3p, const float* __restrict__ b3p, float* __restrict__ out) {
    __shared__ float wl[128];
    const int tid = threadIdx.x;
    if (tid < 128) wl[tid] = w3p[tid];
    __syncthreads();
    const size_t row = (size_t)blockIdx.x * 64 + (tid >> 2);
    const int c0 = (tid & 3) * 8;
    const unsigned short* rowp = a2 + row * 128 + c0;
    float s = 0.f;
#pragma unroll
    for (int i = 0; i < 4; ++i) {
        uint4 u = *(const uint4*)(rowp + i * 32);
        const unsigned short* us = (const unsigned short*)&u;
#pragma unroll
        for (int j = 0; j < 8; ++j) s += bf2f(us[j]) * wl[c0 + i * 32 + j];
    }
    s += __shfl_xor(s, 1);
    s += __shfl_xor(s, 2);
    if ((tid & 3) == 0) out[row] = s + b3p[0];
}

extern "C" void kernel_launch(void* const* d_in, const int* in_sizes, int n_in,
                              void* d_out, int out_size, void* d_ws, size_t ws_size,
                              hipStream_t stream) {
    (void)in_sizes; (void)n_in; (void)out_size; (void)ws_size;
    const float* h   = (const float*)d_in[0];
    const float* e   = (const float*)d_in[1];
    const int*   src = (const int*)d_in[2];
    const int*   dst = (const int*)d_in[3];
    const float* bn0_g = (const float*)d_in[4];
    const float* bn0_b = (const float*)d_in[5];
    const float* W1 = (const float*)d_in[6];
    const float* b1 = (const float*)d_in[7];
    const float* bn1_g = (const float*)d_in[8];
    const float* bn1_b = (const float*)d_in[9];
    const float* W2 = (const float*)d_in[10];
    const float* b2 = (const float*)d_in[11];
    const float* bn2_g = (const float*)d_in[12];
    const float* bn2_b = (const float*)d_in[13];
    const float* W3 = (const float*)d_in[14];
    const float* b3 = (const float*)d_in[15];

    char* ws = (char*)d_ws;
    size_t off = 0;
    auto alloc = [&](size_t bytes) { char* p = ws + off; off += (bytes + 255) & ~(size_t)255; return p; };
    int*   cnt_s = (int*)alloc((size_t)N_NODES * 4);
    int*   cnt_d = (int*)alloc((size_t)N_NODES * 4);
    float* bn0_sum = (float*)alloc(320 * 4);
    float* bn0_sq  = (float*)alloc(320 * 4);
    float* bn1_slots = (float*)alloc(64 * 512 * 4);
    float* bn2_slots = (float*)alloc(64 * 256 * 4);
    const size_t zero_end = off;
    float* scale0 = (float*)alloc(320 * 4);
    float* shift0 = (float*)alloc(320 * 4);
    unsigned short* W1s = (unsigned short*)alloc(256 * 128 * 2);
    unsigned short* W1d = (unsigned short*)alloc(256 * 128 * 2);
    unsigned short* W1e = (unsigned short*)alloc(256 * 64 * 2);
    float* b1p = (float*)alloc(256 * 4);
    unsigned short* W2p = (unsigned short*)alloc(128 * 256 * 2);
    float* b2p = (float*)alloc(128 * 4);
    float* w3p = (float*)alloc(128 * 4);
    float* b3p = (float*)alloc(4);
    unsigned short* Ps = (unsigned short*)alloc((size_t)N_NODES * 256 * 2);
    unsigned short* Pd = (unsigned short*)alloc((size_t)N_NODES * 256 * 2);
    unsigned short* a1 = (unsigned short*)alloc((size_t)N_EDGES * 256 * 2);
    unsigned short* a2 = (unsigned short*)alloc((size_t)N_EDGES * 128 * 2);

    hipMemsetAsync(d_ws, 0, zero_end, stream);
    k_hist<<<(N_EDGES + 255) / 256, 256, 0, stream>>>(src, dst, cnt_s, cnt_d);
    k_estats<<<512, 256, 0, stream>>>(e, bn0_sum, bn0_sq);
    k_hstats<<<200, 256, 0, stream>>>(h, cnt_s, cnt_d, bn0_sum, bn0_sq);
    k_fold0<<<1, 320, 0, stream>>>(bn0_sum, bn0_sq, bn0_g, bn0_b, scale0, shift0);
    k_foldW1<<<1, 320, 0, stream>>>(W1, b1, scale0, shift0, W1s, W1d, W1e, b1p);
    k_P<<<dim3(196, 2), 256, 0, stream>>>(h, W1s, W1d, Ps, Pd);
    k_L1<<<N_EDGES / 256, 256, 0, stream>>>(e, src, dst, Ps, Pd, W1e, b1p, a1, bn1_slots);
    k_fold1<<<1, 256, 0, stream>>>(bn1_slots, bn1_g, bn1_b, W2, b2, W2p, b2p);
    k_L2<<<N_EDGES / 256, 256, 0, stream>>>(a1, W2p, b2p, a2, bn2_slots);
    k_fold2<<<1, 128, 0, stream>>>(bn2_slots, bn2_g, bn2_b, W3, b3, w3p, b3p);
    k_L3<<<N_EDGES / 64, 256, 0, stream>>>(a2, w3p, b3p, (float*)d_out);
}

// Round 6
// 1236.234 us; speedup vs baseline: 1.2168x; 1.2168x over previous
//
#include <hip/hip_runtime.h>

// NNPredictor: edge MLP with BN folded into weights.
// R6: safe rebuild. Keeps tiled layouts (ebf A-tiled, a1t A-tiled, a2c C-cells);
// removes global_load_lds staging and custom asm barriers (R4/R5 NaN suspects).
// k_L1: single LDS tile + two __syncthreads/iter (R2-proven), tail-issued
//       single-set register prefetch (af + gathers) for next chunk.
// k_L2: LDS-free, barrier-free — lanes load A-frags straight from tiled a1t.

#define N_EDGES 800000
#define N_NODES 50000

typedef __attribute__((ext_vector_type(8))) short bf8_t;
typedef __attribute__((ext_vector_type(4))) float f4_t;

__device__ __forceinline__ unsigned short f2bf(float f) {
    unsigned int u = __builtin_bit_cast(unsigned int, f);
    u += 0x7FFFu + ((u >> 16) & 1u);
    return (unsigned short)(u >> 16);
}
__device__ __forceinline__ float bf2f(unsigned short s) {
    unsigned int u = ((unsigned int)s) << 16;
    return __builtin_bit_cast(float, u);
}
__device__ __forceinline__ bf8_t cvt8(f4_t x, f4_t y) {
    bf8_t r;
    r[0] = (short)f2bf(x[0]); r[1] = (short)f2bf(x[1]);
    r[2] = (short)f2bf(x[2]); r[3] = (short)f2bf(x[3]);
    r[4] = (short)f2bf(y[0]); r[5] = (short)f2bf(y[1]);
    r[6] = (short)f2bf(y[2]); r[7] = (short)f2bf(y[3]);
    return r;
}

__global__ __launch_bounds__(256) void k_hist(const int* __restrict__ src, const int* __restrict__ dst,
                                              int* __restrict__ cs, int* __restrict__ cd) {
    int i = blockIdx.x * 256 + threadIdx.x;
    if (i < N_EDGES) {
        atomicAdd(&cs[src[i]], 1);
        atomicAdd(&cd[dst[i]], 1);
    }
}

// e -> bf16 in A-tiled layout [blk16][ks(2)][(row*4+colgrp)][8], fused BN0 e-col stats.
__global__ __launch_bounds__(256) void k_ecvt(const float* __restrict__ e,
        unsigned short* __restrict__ ebf, float* __restrict__ sum, float* __restrict__ sq) {
    const int tid = threadIdx.x;
    const int lane = tid & 63;
    const int cg = tid & 7, rr = tid >> 3;
    f4_t sa = {0.f,0.f,0.f,0.f}, sb = sa, qa = sa, qb = sa;
    for (int r = blockIdx.x * 32 + rr; r < N_EDGES; r += gridDim.x * 32) {
        f4_t va = *(const f4_t*)(e + (size_t)r * 64 + cg * 8);
        f4_t vb = *(const f4_t*)(e + (size_t)r * 64 + cg * 8 + 4);
        sa += va; qa += va * va; sb += vb; qb += vb * vb;
        bf8_t o = cvt8(va, vb);
        *(bf8_t*)(ebf + (size_t)(r >> 4) * 1024 + (cg >> 2) * 512 + (((r & 15) << 2) + (cg & 3)) * 8) = o;
    }
#pragma unroll
    for (int d = 8; d <= 32; d <<= 1) {
#pragma unroll
        for (int j = 0; j < 4; ++j) {
            sa[j] += __shfl_xor(sa[j], d); qa[j] += __shfl_xor(qa[j], d);
            sb[j] += __shfl_xor(sb[j], d); qb[j] += __shfl_xor(qb[j], d);
        }
    }
    __shared__ float red[128];
    if (tid < 128) red[tid] = 0.f;
    __syncthreads();
    if (lane < 8) {
#pragma unroll
        for (int j = 0; j < 4; ++j) {
            atomicAdd(&red[lane * 8 + j], sa[j]);
            atomicAdd(&red[lane * 8 + 4 + j], sb[j]);
            atomicAdd(&red[64 + lane * 8 + j], qa[j]);
            atomicAdd(&red[64 + lane * 8 + 4 + j], qb[j]);
        }
    }
    __syncthreads();
    if (tid < 64) atomicAdd(&sum[256 + tid], red[tid]);
    else if (tid < 128) atomicAdd(&sq[256 + tid - 64], red[tid]);
}

__global__ __launch_bounds__(256) void k_hstats(const float* __restrict__ h,
                                                const int* __restrict__ cs, const int* __restrict__ cd,
                                                float* __restrict__ sum, float* __restrict__ sq) {
    const int tid = threadIdx.x;
    const int c = tid & 127, g = tid >> 7;
    float ss = 0.f, qs = 0.f, sd = 0.f, qd = 0.f;
    for (int n = blockIdx.x * 2 + g; n < N_NODES; n += gridDim.x * 2) {
        float v = h[(size_t)n * 128 + c];
        float a = (float)cs[n], b = (float)cd[n];
        ss += a * v; qs += a * v * v;
        sd += b * v; qd += b * v * v;
    }
    __shared__ float red[256];
    red[tid] = ss; __syncthreads();
    if (tid < 128) atomicAdd(&sum[tid], red[tid] + red[tid + 128]);
    __syncthreads();
    red[tid] = qs; __syncthreads();
    if (tid < 128) atomicAdd(&sq[tid], red[tid] + red[tid + 128]);
    __syncthreads();
    red[tid] = sd; __syncthreads();
    if (tid < 128) atomicAdd(&sum[128 + tid], red[tid] + red[tid + 128]);
    __syncthreads();
    red[tid] = qd; __syncthreads();
    if (tid < 128) atomicAdd(&sq[128 + tid], red[tid] + red[tid + 128]);
}

__global__ __launch_bounds__(320) void k_fold0(const float* __restrict__ sum, const float* __restrict__ sq,
        const float* __restrict__ g0, const float* __restrict__ b0,
        float* __restrict__ scale0, float* __restrict__ shift0) {
    int j = threadIdx.x;
    if (j < 320) {
        const float invE = 1.f / (float)N_EDGES;
        float mu = sum[j] * invE;
        float var = sq[j] * invE - mu * mu;
        float sc = g0[j] * rsqrtf(var + 1e-5f);
        scale0[j] = sc;
        shift0[j] = b0[j] - mu * sc;
    }
}

__global__ __launch_bounds__(320) void k_foldW1(const float* __restrict__ W1, const float* __restrict__ b1,
        const float* __restrict__ scale0, const float* __restrict__ shift0,
        unsigned short* __restrict__ W1s, unsigned short* __restrict__ W1d,
        unsigned short* __restrict__ W1e, float* __restrict__ b1p) {
    __shared__ float sc[320], sh[320];
    const int tid = threadIdx.x;
    if (tid < 320) { sc[tid] = scale0[tid]; sh[tid] = shift0[tid]; }
    __syncthreads();
    if (tid < 256) {
        float acc = b1[tid];
        const float* wr = W1 + (size_t)tid * 320;
        for (int j = 0; j < 320; ++j) {
            float wv = wr[j];
            acc += wv * sh[j];
            unsigned short wb = f2bf(wv * sc[j]);
            if (j < 128) W1s[tid * 128 + j] = wb;
            else if (j < 256) W1d[tid * 128 + (j - 128)] = wb;
            else W1e[tid * 64 + (j - 256)] = wb;
        }
        b1p[tid] = acc;
    }
}

// P = h @ W'^T : M=50000 (256/block), N=256, K=128. Row-major bf16 output.
__global__ __launch_bounds__(256) void k_P(const float* __restrict__ h,
        const unsigned short* __restrict__ W1s, const unsigned short* __restrict__ W1d,
        unsigned short* __restrict__ Ps, unsigned short* __restrict__ Pd) {
    __shared__ unsigned short tile[16 * 264];
    const int tid = threadIdx.x;
    const int w = tid >> 6, lane = tid & 63, quad = lane >> 4, l15 = lane & 15;
    const unsigned short* W = blockIdx.y ? W1d : W1s;
    unsigned short* P = blockIdx.y ? Pd : Ps;
    const size_t base = (size_t)blockIdx.x * 256;
    bf8_t bfr[4][4];
#pragma unroll
    for (int j = 0; j < 4; ++j) {
        const unsigned short* wp = W + (size_t)((w * 4 + j) * 16 + l15) * 128 + quad * 8;
#pragma unroll
        for (int ks = 0; ks < 4; ++ks) bfr[j][ks] = *(const bf8_t*)(wp + ks * 32);
    }
    const int erow = tid >> 4, ex = tid & 15;
    for (int mc = 0; mc < 16; ++mc) {
        const size_t row0 = base + mc * 16;
        size_t ar = row0 + l15; if (ar >= N_NODES) ar = N_NODES - 1;
        const float* hp = h + ar * 128 + quad * 8;
        bf8_t af[4];
#pragma unroll
        for (int ks = 0; ks < 4; ++ks)
            af[ks] = cvt8(*(const f4_t*)(hp + ks * 32), *(const f4_t*)(hp + ks * 32 + 4));
#pragma unroll
        for (int j = 0; j < 4; ++j) {
            f4_t t = {0.f, 0.f, 0.f, 0.f};
#pragma unroll
            for (int ks = 0; ks < 4; ++ks)
                t = __builtin_amdgcn_mfma_f32_16x16x32_bf16(af[ks], bfr[j][ks], t, 0, 0, 0);
#pragma unroll
            for (int r = 0; r < 4; ++r)
                tile[(quad * 4 + r) * 264 + (w * 4 + j) * 16 + l15] = f2bf(t[r]);
        }
        __syncthreads();
        const size_t orow = row0 + erow;
        if (orow < N_NODES) {
            uint4 v0 = *(const uint4*)(tile + erow * 264 + ex * 16);
            uint4 v1 = *(const uint4*)(tile + erow * 264 + ex * 16 + 8);
            *(uint4*)(P + orow * 256 + ex * 16) = v0;
            *(uint4*)(P + orow * 256 + ex * 16 + 8) = v1;
        }
        __syncthreads();
    }
}

// a1 = ReLU(e@W1e' + Ps[src] + Pd[dst] + b1'); BN1 stats.
// Single LDS tile, two __syncthreads per iter (proven pattern); next chunk's
// af + gathers issued at iteration tail (single register set, no dbuf).
__global__ __launch_bounds__(256) void k_L1(const unsigned short* __restrict__ ebf,
        const int* __restrict__ src, const int* __restrict__ dst,
        const unsigned short* __restrict__ Ps, const unsigned short* __restrict__ Pd,
        const unsigned short* __restrict__ W1e, const float* __restrict__ b1p,
        unsigned short* __restrict__ a1t, float* __restrict__ slots) {
    __shared__ unsigned short tile[16 * 264];
    __shared__ int sIdx[256], dIdx[256];
    __shared__ float bn[512];
    const int tid = threadIdx.x;
    const int w = tid >> 6, lane = tid & 63, quad = lane >> 4, l15 = lane & 15;
    const int perm = l15 * 4 + quad;
    const size_t base = (size_t)blockIdx.x * 256;
    const size_t blk16 = (size_t)blockIdx.x * 16;
    bn[tid] = 0.f; bn[tid + 256] = 0.f;
    sIdx[tid] = src[base + tid];
    dIdx[tid] = dst[base + tid];
    bf8_t bfr[4][2];
    float bias4[4];
#pragma unroll
    for (int j = 0; j < 4; ++j) {
        const unsigned short* wp = W1e + (size_t)((w * 4 + j) * 16 + l15) * 64 + quad * 8;
        bfr[j][0] = *(const bf8_t*)(wp);
        bfr[j][1] = *(const bf8_t*)(wp + 32);
        bias4[j] = b1p[(w * 4 + j) * 16 + l15];
    }
    const int erow = tid >> 4, ex = tid & 15;
    float sreg[2][8], qreg[2][8];
#pragma unroll
    for (int i = 0; i < 2; ++i)
#pragma unroll
        for (int j = 0; j < 8; ++j) { sreg[i][j] = 0.f; qreg[i][j] = 0.f; }
    __syncthreads();  // publish sIdx/dIdx
    // prologue: loads for chunk 0 (single register set)
    bf8_t a0, a1f;
    uint4 gs0, gs1, gd0, gd1;
    {
        const unsigned short* ap = ebf + blk16 * 1024 + perm * 8;
        a0 = *(const bf8_t*)(ap);
        a1f = *(const bf8_t*)(ap + 512);
        const size_t sr = (size_t)sIdx[erow] * 256, dr = (size_t)dIdx[erow] * 256;
        gs0 = *(const uint4*)(Ps + sr + ex * 8);
        gs1 = *(const uint4*)(Ps + sr + ex * 8 + 128);
        gd0 = *(const uint4*)(Pd + dr + ex * 8);
        gd1 = *(const uint4*)(Pd + dr + ex * 8 + 128);
    }
    for (int mc = 0; mc < 16; ++mc) {
        __syncthreads();  // A: all waves done reading tile (prev iter)
#pragma unroll
        for (int j = 0; j < 4; ++j) {
            f4_t t = {0.f, 0.f, 0.f, 0.f};
            t = __builtin_amdgcn_mfma_f32_16x16x32_bf16(a0, bfr[j][0], t, 0, 0, 0);
            t = __builtin_amdgcn_mfma_f32_16x16x32_bf16(a1f, bfr[j][1], t, 0, 0, 0);
#pragma unroll
            for (int r = 0; r < 4; ++r)
                tile[(quad * 4 + r) * 264 + (w * 4 + j) * 16 + l15] = f2bf(t[r] + bias4[j]);
        }
        __syncthreads();  // B: tile complete
        unsigned short* outp = a1t + (blk16 + mc) * 4096;
#pragma unroll
        for (int i = 0; i < 2; ++i) {
            uint4 tv = *(const uint4*)(&tile[erow * 264 + ex * 8 + 128 * i]);
            const unsigned short* tu = (const unsigned short*)&tv;
            const unsigned short* su = (const unsigned short*)(i ? &gs1 : &gs0);
            const unsigned short* du = (const unsigned short*)(i ? &gd1 : &gd0);
            unsigned short ov[8];
#pragma unroll
            for (int j = 0; j < 8; ++j) {
                float v = bf2f(tu[j]) + bf2f(su[j]) + bf2f(du[j]);
                v = fmaxf(v, 0.f);
                ov[j] = f2bf(v);
                sreg[i][j] += v; qreg[i][j] += v * v;
            }
            *(uint4*)(outp + ((ex >> 2) + 4 * i) * 512 + (erow * 4 + (ex & 3)) * 8) = *(const uint4*)ov;
        }
        if (mc < 15) {  // tail-issue loads for chunk mc+1 (regs now free)
            const unsigned short* ap = ebf + (blk16 + mc + 1) * 1024 + perm * 8;
            a0 = *(const bf8_t*)(ap);
            a1f = *(const bf8_t*)(ap + 512);
            const size_t sr = (size_t)sIdx[(mc + 1) * 16 + erow] * 256;
            const size_t dr = (size_t)dIdx[(mc + 1) * 16 + erow] * 256;
            gs0 = *(const uint4*)(Ps + sr + ex * 8);
            gs1 = *(const uint4*)(Ps + sr + ex * 8 + 128);
            gd0 = *(const uint4*)(Pd + dr + ex * 8);
            gd1 = *(const uint4*)(Pd + dr + ex * 8 + 128);
        }
    }
#pragma unroll
    for (int i = 0; i < 2; ++i)
#pragma unroll
        for (int j = 0; j < 8; ++j) {
            const int c = ex * 8 + 128 * i + j;
            atomicAdd(&bn[c], sreg[i][j]);
            atomicAdd(&bn[256 + c], qreg[i][j]);
        }
    __syncthreads();
    float* sl = slots + (size_t)(blockIdx.x & 63) * 512;
    atomicAdd(&sl[tid], bn[tid]);
    atomicAdd(&sl[tid + 256], bn[tid + 256]);
}

__global__ __launch_bounds__(256) void k_fold1(const float* __restrict__ slots,
        const float* __restrict__ g1, const float* __restrict__ b1n,
        const float* __restrict__ W2, const float* __restrict__ b2,
        unsigned short* __restrict__ W2p, float* __restrict__ b2p) {
    __shared__ float sc[256], sh[256];
    const int tid = threadIdx.x;
    float S = 0.f, Q = 0.f;
    for (int s = 0; s < 64; ++s) { S += slots[s * 512 + tid]; Q += slots[s * 512 + 256 + tid]; }
    const float invE = 1.f / (float)N_EDGES;
    float mu = S * invE;
    float var = Q * invE - mu * mu;
    float scl = g1[tid] * rsqrtf(var + 1e-5f);
    sc[tid] = scl; sh[tid] = b1n[tid] - mu * scl;
    __syncthreads();
    if (tid < 128) {
        float acc = b2[tid];
        const float* wr = W2 + (size_t)tid * 256;
        for (int j = 0; j < 256; ++j) {
            float wv = wr[j];
            acc += wv * sh[j];
            W2p[tid * 256 + j] = f2bf(wv * sc[j]);
        }
        b2p[tid] = acc;
    }
}

// a2 = ReLU(a1 @ W2'^T + b2'); BN2 stats. LDS-free, barrier-free: a1t is
// already in A-frag order, each lane loads its own 8 contiguous 16B frags.
__global__ __launch_bounds__(256) void k_L2(const unsigned short* __restrict__ a1t,
        const unsigned short* __restrict__ W2p, const float* __restrict__ b2p,
        unsigned short* __restrict__ a2c, float* __restrict__ slots) {
    const int tid = threadIdx.x;
    const int w = tid >> 6, lane = tid & 63, quad = lane >> 4, l15 = lane & 15;
    const int perm = l15 * 4 + quad;
    const size_t blk16 = (size_t)blockIdx.x * 16;
    bf8_t bfr[2][8];
    float bias[2];
#pragma unroll
    for (int j = 0; j < 2; ++j) {
        const unsigned short* wp = W2p + (size_t)((w * 2 + j) * 16 + l15) * 256 + quad * 8;
#pragma unroll
        for (int ks = 0; ks < 8; ++ks) bfr[j][ks] = *(const bf8_t*)(wp + ks * 32);
        bias[j] = b2p[(w * 2 + j) * 16 + l15];
    }
    float s0 = 0.f, q0 = 0.f, s1 = 0.f, q1 = 0.f;
    for (int mc = 0; mc < 16; ++mc) {
        const unsigned short* ap = a1t + (blk16 + mc) * 4096 + perm * 8;
        bf8_t a[8];
#pragma unroll
        for (int ks = 0; ks < 8; ++ks) a[ks] = *(const bf8_t*)(ap + ks * 512);
        f4_t acc0 = {0.f, 0.f, 0.f, 0.f}, acc1 = acc0;
#pragma unroll
        for (int ks = 0; ks < 8; ++ks) {
            acc0 = __builtin_amdgcn_mfma_f32_16x16x32_bf16(a[ks], bfr[0][ks], acc0, 0, 0, 0);
            acc1 = __builtin_amdgcn_mfma_f32_16x16x32_bf16(a[ks], bfr[1][ks], acc1, 0, 0, 0);
        }
        unsigned short* outp = a2c + (blk16 + mc) * 2048;
        unsigned short pv[4];
#pragma unroll
        for (int r = 0; r < 4; ++r) {
            float v = fmaxf(acc0[r] + bias[0], 0.f);
            pv[r] = f2bf(v); s0 += v; q0 += v * v;
        }
        *(uint2*)(outp + (((w * 2) * 16 + l15) * 4 + quad) * 4) = *(const uint2*)pv;
#pragma unroll
        for (int r = 0; r < 4; ++r) {
            float v = fmaxf(acc1[r] + bias[1], 0.f);
            pv[r] = f2bf(v); s1 += v; q1 += v * v;
        }
        *(uint2*)(outp + (((w * 2 + 1) * 16 + l15) * 4 + quad) * 4) = *(const uint2*)pv;
    }
    s0 += __shfl_xor(s0, 16); s0 += __shfl_xor(s0, 32);
    q0 += __shfl_xor(q0, 16); q0 += __shfl_xor(q0, 32);
    s1 += __shfl_xor(s1, 16); s1 += __shfl_xor(s1, 32);
    q1 += __shfl_xor(q1, 16); q1 += __shfl_xor(q1, 32);
    if (lane < 16) {
        float* sl = slots + (size_t)(blockIdx.x & 63) * 256;
        const int c0 = (w * 2) * 16 + l15;
        atomicAdd(&sl[c0], s0); atomicAdd(&sl[128 + c0], q0);
        atomicAdd(&sl[c0 + 16], s1); atomicAdd(&sl[128 + c0 + 16], q1);
    }
}

__global__ __launch_bounds__(128) void k_fold2(const float* __restrict__ slots,
        const float* __restrict__ g2, const float* __restrict__ b2n,
        const float* __restrict__ W3, const float* __restrict__ b3,
        float* __restrict__ w3p, float* __restrict__ b3p) {
    __shared__ float red[128];
    const int tid = threadIdx.x;
    float S = 0.f, Q = 0.f;
    for (int s = 0; s < 64; ++s) { S += slots[s * 256 + tid]; Q += slots[s * 256 + 128 + tid]; }
    const float invE = 1.f / (float)N_EDGES;
    float mu = S * invE;
    float var = Q * invE - mu * mu;
    float scl = g2[tid] * rsqrtf(var + 1e-5f);
    float shf = b2n[tid] - mu * scl;
    w3p[tid] = W3[tid] * scl;
    red[tid] = W3[tid] * shf;
    __syncthreads();
    for (int st = 64; st > 0; st >>= 1) {
        if (tid < st) red[tid] += red[tid + st];
        __syncthreads();
    }
    if (tid == 0) b3p[0] = b3[0] + red[0];
}

// out = a2 . w3' + b3' from C-layout cells; wave per 16-row block, shuffle reduce.
__global__ __launch_bounds__(256) void k_L3(const unsigned short* __restrict__ a2c,
        const float* __restrict__ w3p, const float* __restrict__ b3p, float* __restrict__ out) {
    __shared__ float wl[128];
    const int tid = threadIdx.x;
    if (tid < 128) wl[tid] = w3p[tid];
    __syncthreads();
    const int w = tid >> 6, lane = tid & 63, q = lane >> 4, c = lane & 15;
    const float bb = b3p[0];
#pragma unroll
    for (int i = 0; i < 4; ++i) {
        const size_t b = (size_t)blockIdx.x * 16 + w * 4 + i;
        const unsigned short* bp = a2c + b * 2048 + c * 16 + q * 4;
        float a0 = 0.f, a1r = 0.f, a2r = 0.f, a3r = 0.f;
#pragma unroll
        for (int jt = 0; jt < 8; ++jt) {
            uint2 v = *(const uint2*)(bp + jt * 256);
            const unsigned short* u = (const unsigned short*)&v;
            const float wv = wl[jt * 16 + c];
            a0 += bf2f(u[0]) * wv; a1r += bf2f(u[1]) * wv;
            a2r += bf2f(u[2]) * wv; a3r += bf2f(u[3]) * wv;
        }
#pragma unroll
        for (int d = 1; d <= 8; d <<= 1) {
            a0 += __shfl_xor(a0, d); a1r += __shfl_xor(a1r, d);
            a2r += __shfl_xor(a2r, d); a3r += __shfl_xor(a3r, d);
        }
        if (c == 0) {
            f4_t o = {a0 + bb, a1r + bb, a2r + bb, a3r + bb};
            *(f4_t*)(out + b * 16 + q * 4) = o;
        }
    }
}

extern "C" void kernel_launch(void* const* d_in, const int* in_sizes, int n_in,
                              void* d_out, int out_size, void* d_ws, size_t ws_size,
                              hipStream_t stream) {
    (void)in_sizes; (void)n_in; (void)out_size; (void)ws_size;
    const float* h   = (const float*)d_in[0];
    const float* e   = (const float*)d_in[1];
    const int*   src = (const int*)d_in[2];
    const int*   dst = (const int*)d_in[3];
    const float* bn0_g = (const float*)d_in[4];
    const float* bn0_b = (const float*)d_in[5];
    const float* W1 = (const float*)d_in[6];
    const float* b1 = (const float*)d_in[7];
    const float* bn1_g = (const float*)d_in[8];
    const float* bn1_b = (const float*)d_in[9];
    const float* W2 = (const float*)d_in[10];
    const float* b2 = (const float*)d_in[11];
    const float* bn2_g = (const float*)d_in[12];
    const float* bn2_b = (const float*)d_in[13];
    const float* W3 = (const float*)d_in[14];
    const float* b3 = (const float*)d_in[15];

    char* ws = (char*)d_ws;
    size_t off = 0;
    auto alloc = [&](size_t bytes) { char* p = ws + off; off += (bytes + 255) & ~(size_t)255; return p; };
    int*   cnt_s = (int*)alloc((size_t)N_NODES * 4);
    int*   cnt_d = (int*)alloc((size_t)N_NODES * 4);
    float* bn0_sum = (float*)alloc(320 * 4);
    float* bn0_sq  = (float*)alloc(320 * 4);
    float* bn1_slots = (float*)alloc(64 * 512 * 4);
    float* bn2_slots = (float*)alloc(64 * 256 * 4);
    const size_t zero_end = off;
    float* scale0 = (float*)alloc(320 * 4);
    float* shift0 = (float*)alloc(320 * 4);
    unsigned short* W1s = (unsigned short*)alloc(256 * 128 * 2);
    unsigned short* W1d = (unsigned short*)alloc(256 * 128 * 2);
    unsigned short* W1e = (unsigned short*)alloc(256 * 64 * 2);
    float* b1p = (float*)alloc(256 * 4);
    unsigned short* W2p = (unsigned short*)alloc(128 * 256 * 2);
    float* b2p = (float*)alloc(128 * 4);
    float* w3p = (float*)alloc(128 * 4);
    float* b3p = (float*)alloc(4);
    unsigned short* Ps = (unsigned short*)alloc((size_t)N_NODES * 256 * 2);
    unsigned short* Pd = (unsigned short*)alloc((size_t)N_NODES * 256 * 2);
    unsigned short* a1t = (unsigned short*)alloc((size_t)(N_EDGES / 16) * 8192);
    // ebf (102.4 MB, dead after k_L1) aliases a2c (204.8 MB, written in k_L2)
    unsigned short* shared_buf = (unsigned short*)alloc((size_t)(N_EDGES / 16) * 4096);
    unsigned short* ebf = shared_buf;
    unsigned short* a2c = shared_buf;

    hipMemsetAsync(d_ws, 0, zero_end, stream);
    k_hist<<<(N_EDGES + 255) / 256, 256, 0, stream>>>(src, dst, cnt_s, cnt_d);
    k_ecvt<<<256, 256, 0, stream>>>(e, ebf, bn0_sum, bn0_sq);
    k_hstats<<<200, 256, 0, stream>>>(h, cnt_s, cnt_d, bn0_sum, bn0_sq);
    k_fold0<<<1, 320, 0, stream>>>(bn0_sum, bn0_sq, bn0_g, bn0_b, scale0, shift0);
    k_foldW1<<<1, 320, 0, stream>>>(W1, b1, scale0, shift0, W1s, W1d, W1e, b1p);
    k_P<<<dim3(196, 2), 256, 0, stream>>>(h, W1s, W1d, Ps, Pd);
    k_L1<<<N_EDGES / 256, 256, 0, stream>>>(ebf, src, dst, Ps, Pd, W1e, b1p, a1t, bn1_slots);
    k_fold1<<<1, 256, 0, stream>>>(bn1_slots, bn1_g, bn1_b, W2, b2, W2p, b2p);
    k_L2<<<N_EDGES / 256, 256, 0, stream>>>(a1t, W2p, b2p, a2c, bn2_slots);
    k_fold2<<<1, 128, 0, stream>>>(bn2_slots, bn2_g, bn2_b, W3, b3, w3p, b3p);
    k_L3<<<N_EDGES / 256, 256, 0, stream>>>(a2c, w3p, b3p, (float*)d_out);
}

// Round 7
// 1051.000 us; speedup vs baseline: 1.4313x; 1.1762x over previous
//
#include <hip/hip_runtime.h>

// NNPredictor: edge MLP with BN folded into weights.
// R7: a1 never touches HBM. Pass A (k_stats1): barrier-free register-only
// BN1 stats (GEMM1 C-layout + scalar u16 gathers). Pass B (k_L12): recompute
// a1 chunk (R6-proven tile path) -> A-tiled LDS (dbuf) -> GEMM2 (W2p in regs)
// -> a2 C-cells + BN2 stats. k_L2 kernel deleted.

#define N_EDGES 800000
#define N_NODES 50000

typedef __attribute__((ext_vector_type(8))) short bf8_t;
typedef __attribute__((ext_vector_type(4))) float f4_t;

__device__ __forceinline__ unsigned short f2bf(float f) {
    unsigned int u = __builtin_bit_cast(unsigned int, f);
    u += 0x7FFFu + ((u >> 16) & 1u);
    return (unsigned short)(u >> 16);
}
__device__ __forceinline__ float bf2f(unsigned short s) {
    unsigned int u = ((unsigned int)s) << 16;
    return __builtin_bit_cast(float, u);
}
__device__ __forceinline__ bf8_t cvt8(f4_t x, f4_t y) {
    bf8_t r;
    r[0] = (short)f2bf(x[0]); r[1] = (short)f2bf(x[1]);
    r[2] = (short)f2bf(x[2]); r[3] = (short)f2bf(x[3]);
    r[4] = (short)f2bf(y[0]); r[5] = (short)f2bf(y[1]);
    r[6] = (short)f2bf(y[2]); r[7] = (short)f2bf(y[3]);
    return r;
}

__global__ __launch_bounds__(256) void k_hist(const int* __restrict__ src, const int* __restrict__ dst,
                                              int* __restrict__ cs, int* __restrict__ cd) {
    int i = blockIdx.x * 256 + threadIdx.x;
    if (i < N_EDGES) {
        atomicAdd(&cs[src[i]], 1);
        atomicAdd(&cd[dst[i]], 1);
    }
}

// e -> bf16 in A-tiled layout [blk16][ks(2)][(row*4+colgrp)][8], fused BN0 e-col stats.
__global__ __launch_bounds__(256) void k_ecvt(const float* __restrict__ e,
        unsigned short* __restrict__ ebf, float* __restrict__ sum, float* __restrict__ sq) {
    const int tid = threadIdx.x;
    const int lane = tid & 63;
    const int cg = tid & 7, rr = tid >> 3;
    f4_t sa = {0.f,0.f,0.f,0.f}, sb = sa, qa = sa, qb = sa;
    for (int r = blockIdx.x * 32 + rr; r < N_EDGES; r += gridDim.x * 32) {
        f4_t va = *(const f4_t*)(e + (size_t)r * 64 + cg * 8);
        f4_t vb = *(const f4_t*)(e + (size_t)r * 64 + cg * 8 + 4);
        sa += va; qa += va * va; sb += vb; qb += vb * vb;
        bf8_t o = cvt8(va, vb);
        *(bf8_t*)(ebf + (size_t)(r >> 4) * 1024 + (cg >> 2) * 512 + (((r & 15) << 2) + (cg & 3)) * 8) = o;
    }
#pragma unroll
    for (int d = 8; d <= 32; d <<= 1) {
#pragma unroll
        for (int j = 0; j < 4; ++j) {
            sa[j] += __shfl_xor(sa[j], d); qa[j] += __shfl_xor(qa[j], d);
            sb[j] += __shfl_xor(sb[j], d); qb[j] += __shfl_xor(qb[j], d);
        }
    }
    __shared__ float red[128];
    if (tid < 128) red[tid] = 0.f;
    __syncthreads();
    if (lane < 8) {
#pragma unroll
        for (int j = 0; j < 4; ++j) {
            atomicAdd(&red[lane * 8 + j], sa[j]);
            atomicAdd(&red[lane * 8 + 4 + j], sb[j]);
            atomicAdd(&red[64 + lane * 8 + j], qa[j]);
            atomicAdd(&red[64 + lane * 8 + 4 + j], qb[j]);
        }
    }
    __syncthreads();
    if (tid < 64) atomicAdd(&sum[256 + tid], red[tid]);
    else if (tid < 128) atomicAdd(&sq[256 + tid - 64], red[tid]);
}

__global__ __launch_bounds__(256) void k_hstats(const float* __restrict__ h,
                                                const int* __restrict__ cs, const int* __restrict__ cd,
                                                float* __restrict__ sum, float* __restrict__ sq) {
    const int tid = threadIdx.x;
    const int c = tid & 127, g = tid >> 7;
    float ss = 0.f, qs = 0.f, sd = 0.f, qd = 0.f;
    for (int n = blockIdx.x * 2 + g; n < N_NODES; n += gridDim.x * 2) {
        float v = h[(size_t)n * 128 + c];
        float a = (float)cs[n], b = (float)cd[n];
        ss += a * v; qs += a * v * v;
        sd += b * v; qd += b * v * v;
    }
    __shared__ float red[256];
    red[tid] = ss; __syncthreads();
    if (tid < 128) atomicAdd(&sum[tid], red[tid] + red[tid + 128]);
    __syncthreads();
    red[tid] = qs; __syncthreads();
    if (tid < 128) atomicAdd(&sq[tid], red[tid] + red[tid + 128]);
    __syncthreads();
    red[tid] = sd; __syncthreads();
    if (tid < 128) atomicAdd(&sum[128 + tid], red[tid] + red[tid + 128]);
    __syncthreads();
    red[tid] = qd; __syncthreads();
    if (tid < 128) atomicAdd(&sq[128 + tid], red[tid] + red[tid + 128]);
}

__global__ __launch_bounds__(320) void k_fold0(const float* __restrict__ sum, const float* __restrict__ sq,
        const float* __restrict__ g0, const float* __restrict__ b0,
        float* __restrict__ scale0, float* __restrict__ shift0) {
    int j = threadIdx.x;
    if (j < 320) {
        const float invE = 1.f / (float)N_EDGES;
        float mu = sum[j] * invE;
        float var = sq[j] * invE - mu * mu;
        float sc = g0[j] * rsqrtf(var + 1e-5f);
        scale0[j] = sc;
        shift0[j] = b0[j] - mu * sc;
    }
}

__global__ __launch_bounds__(320) void k_foldW1(const float* __restrict__ W1, const float* __restrict__ b1,
        const float* __restrict__ scale0, const float* __restrict__ shift0,
        unsigned short* __restrict__ W1s, unsigned short* __restrict__ W1d,
        unsigned short* __restrict__ W1e, float* __restrict__ b1p) {
    __shared__ float sc[320], sh[320];
    const int tid = threadIdx.x;
    if (tid < 320) { sc[tid] = scale0[tid]; sh[tid] = shift0[tid]; }
    __syncthreads();
    if (tid < 256) {
        float acc = b1[tid];
        const float* wr = W1 + (size_t)tid * 320;
        for (int j = 0; j < 320; ++j) {
            float wv = wr[j];
            acc += wv * sh[j];
            unsigned short wb = f2bf(wv * sc[j]);
            if (j < 128) W1s[tid * 128 + j] = wb;
            else if (j < 256) W1d[tid * 128 + (j - 128)] = wb;
            else W1e[tid * 64 + (j - 256)] = wb;
        }
        b1p[tid] = acc;
    }
}

// P = h @ W'^T : M=50000 (256/block), N=256, K=128. Row-major bf16 output.
__global__ __launch_bounds__(256) void k_P(const float* __restrict__ h,
        const unsigned short* __restrict__ W1s, const unsigned short* __restrict__ W1d,
        unsigned short* __restrict__ Ps, unsigned short* __restrict__ Pd) {
    __shared__ unsigned short tile[16 * 264];
    const int tid = threadIdx.x;
    const int w = tid >> 6, lane = tid & 63, quad = lane >> 4, l15 = lane & 15;
    const unsigned short* W = blockIdx.y ? W1d : W1s;
    unsigned short* P = blockIdx.y ? Pd : Ps;
    const size_t base = (size_t)blockIdx.x * 256;
    bf8_t bfr[4][4];
#pragma unroll
    for (int j = 0; j < 4; ++j) {
        const unsigned short* wp = W + (size_t)((w * 4 + j) * 16 + l15) * 128 + quad * 8;
#pragma unroll
        for (int ks = 0; ks < 4; ++ks) bfr[j][ks] = *(const bf8_t*)(wp + ks * 32);
    }
    const int erow = tid >> 4, ex = tid & 15;
    for (int mc = 0; mc < 16; ++mc) {
        const size_t row0 = base + mc * 16;
        size_t ar = row0 + l15; if (ar >= N_NODES) ar = N_NODES - 1;
        const float* hp = h + ar * 128 + quad * 8;
        bf8_t af[4];
#pragma unroll
        for (int ks = 0; ks < 4; ++ks)
            af[ks] = cvt8(*(const f4_t*)(hp + ks * 32), *(const f4_t*)(hp + ks * 32 + 4));
#pragma unroll
        for (int j = 0; j < 4; ++j) {
            f4_t t = {0.f, 0.f, 0.f, 0.f};
#pragma unroll
            for (int ks = 0; ks < 4; ++ks)
                t = __builtin_amdgcn_mfma_f32_16x16x32_bf16(af[ks], bfr[j][ks], t, 0, 0, 0);
#pragma unroll
            for (int r = 0; r < 4; ++r)
                tile[(quad * 4 + r) * 264 + (w * 4 + j) * 16 + l15] = f2bf(t[r]);
        }
        __syncthreads();
        const size_t orow = row0 + erow;
        if (orow < N_NODES) {
            uint4 v0 = *(const uint4*)(tile + erow * 264 + ex * 16);
            uint4 v1 = *(const uint4*)(tile + erow * 264 + ex * 16 + 8);
            *(uint4*)(P + orow * 256 + ex * 16) = v0;
            *(uint4*)(P + orow * 256 + ex * 16 + 8) = v1;
        }
        __syncthreads();
    }
}

// Pass A: BN1 stats only, no stores. GEMM1 accs stay in C-layout registers;
// gathers are scalar u16 (quad-broadcast row index, 16-lane 32B segments).
// One barrier total (index publish).
__global__ __launch_bounds__(256) void k_stats1(const unsigned short* __restrict__ ebf,
        const int* __restrict__ src, const int* __restrict__ dst,
        const unsigned short* __restrict__ Ps, const unsigned short* __restrict__ Pd,
        const unsigned short* __restrict__ W1e, const float* __restrict__ b1p,
        float* __restrict__ slots) {
    __shared__ int sIdx[256], dIdx[256];
    const int tid = threadIdx.x;
    const int w = tid >> 6, lane = tid & 63, quad = lane >> 4, l15 = lane & 15;
    const int perm = l15 * 4 + quad;
    const size_t base = (size_t)blockIdx.x * 256;
    const size_t blk16 = (size_t)blockIdx.x * 16;
    sIdx[tid] = src[base + tid];
    dIdx[tid] = dst[base + tid];
    bf8_t bfr[4][2];
    float bias4[4];
#pragma unroll
    for (int j = 0; j < 4; ++j) {
        const unsigned short* wp = W1e + (size_t)((w * 4 + j) * 16 + l15) * 64 + quad * 8;
        bfr[j][0] = *(const bf8_t*)(wp);
        bfr[j][1] = *(const bf8_t*)(wp + 32);
        bias4[j] = b1p[(w * 4 + j) * 16 + l15];
    }
    const int cb = w * 64 + l15;  // this lane's column for j-tile 0
    float s[4] = {0.f, 0.f, 0.f, 0.f}, q[4] = {0.f, 0.f, 0.f, 0.f};
    __syncthreads();  // publish sIdx/dIdx
    bf8_t af0, af1;
    {
        const unsigned short* ap = ebf + blk16 * 1024 + perm * 8;
        af0 = *(const bf8_t*)(ap);
        af1 = *(const bf8_t*)(ap + 512);
    }
    for (int mc = 0; mc < 16; ++mc) {
        const int r0 = mc * 16 + quad * 4;
        // scalar gathers: 4 rows x 4 j-cols x {Ps,Pd}
        const unsigned short* p0 = Ps + (size_t)sIdx[r0 + 0] * 256 + cb;
        const unsigned short* p1 = Ps + (size_t)sIdx[r0 + 1] * 256 + cb;
        const unsigned short* p2 = Ps + (size_t)sIdx[r0 + 2] * 256 + cb;
        const unsigned short* p3 = Ps + (size_t)sIdx[r0 + 3] * 256 + cb;
        const unsigned short* d0 = Pd + (size_t)dIdx[r0 + 0] * 256 + cb;
        const unsigned short* d1 = Pd + (size_t)dIdx[r0 + 1] * 256 + cb;
        const unsigned short* d2 = Pd + (size_t)dIdx[r0 + 2] * 256 + cb;
        const unsigned short* d3 = Pd + (size_t)dIdx[r0 + 3] * 256 + cb;
        unsigned short ps[4][4], pd[4][4];
#pragma unroll
        for (int j = 0; j < 4; ++j) {
            ps[0][j] = p0[j * 16]; ps[1][j] = p1[j * 16];
            ps[2][j] = p2[j * 16]; ps[3][j] = p3[j * 16];
            pd[0][j] = d0[j * 16]; pd[1][j] = d1[j * 16];
            pd[2][j] = d2[j * 16]; pd[3][j] = d3[j * 16];
        }
        f4_t acc[4];
#pragma unroll
        for (int j = 0; j < 4; ++j) {
            f4_t t = {0.f, 0.f, 0.f, 0.f};
            t = __builtin_amdgcn_mfma_f32_16x16x32_bf16(af0, bfr[j][0], t, 0, 0, 0);
            acc[j] = __builtin_amdgcn_mfma_f32_16x16x32_bf16(af1, bfr[j][1], t, 0, 0, 0);
        }
        if (mc < 15) {  // prefetch next A-frags
            const unsigned short* ap = ebf + (blk16 + mc + 1) * 1024 + perm * 8;
            af0 = *(const bf8_t*)(ap);
            af1 = *(const bf8_t*)(ap + 512);
        }
#pragma unroll
        for (int j = 0; j < 4; ++j)
#pragma unroll
            for (int r = 0; r < 4; ++r) {
                float v = acc[j][r] + bf2f(ps[r][j]) + bf2f(pd[r][j]) + bias4[j];
                v = fmaxf(v, 0.f);
                s[j] += v; q[j] += v * v;
            }
    }
#pragma unroll
    for (int j = 0; j < 4; ++j) {
        s[j] += __shfl_xor(s[j], 16); s[j] += __shfl_xor(s[j], 32);
        q[j] += __shfl_xor(q[j], 16); q[j] += __shfl_xor(q[j], 32);
    }
    if (lane < 16) {
        float* sl = slots + (size_t)(blockIdx.x & 63) * 512;
#pragma unroll
        for (int j = 0; j < 4; ++j) {
            atomicAdd(&sl[cb + j * 16], s[j]);
            atomicAdd(&sl[256 + cb + j * 16], q[j]);
        }
    }
}

__global__ __launch_bounds__(256) void k_fold1(const float* __restrict__ slots,
        const float* __restrict__ g1, const float* __restrict__ b1n,
        const float* __restrict__ W2, const float* __restrict__ b2,
        unsigned short* __restrict__ W2p, float* __restrict__ b2p) {
    __shared__ float sc[256], sh[256];
    const int tid = threadIdx.x;
    float S = 0.f, Q = 0.f;
    for (int s = 0; s < 64; ++s) { S += slots[s * 512 + tid]; Q += slots[s * 512 + 256 + tid]; }
    const float invE = 1.f / (float)N_EDGES;
    float mu = S * invE;
    float var = Q * invE - mu * mu;
    float scl = g1[tid] * rsqrtf(var + 1e-5f);
    sc[tid] = scl; sh[tid] = b1n[tid] - mu * scl;
    __syncthreads();
    if (tid < 128) {
        float acc = b2[tid];
        const float* wr = W2 + (size_t)tid * 256;
        for (int j = 0; j < 256; ++j) {
            float wv = wr[j];
            acc += wv * sh[j];
            W2p[tid * 256 + j] = f2bf(wv * sc[j]);
        }
        b2p[tid] = acc;
    }
}

// Pass B: recompute a1 chunk (GEMM1 -> tile1 -> combine) into A-tiled LDS
// (double-buffered tile2), then GEMM2 (W2p in regs) -> a2 C-cells + BN2 stats.
// 2 barriers per chunk.
__global__ __launch_bounds__(256) void k_L12(const unsigned short* __restrict__ ebf,
        const int* __restrict__ src, const int* __restrict__ dst,
        const unsigned short* __restrict__ Ps, const unsigned short* __restrict__ Pd,
        const unsigned short* __restrict__ W1e, const float* __restrict__ b1p,
        const unsigned short* __restrict__ W2p, const float* __restrict__ b2p,
        unsigned short* __restrict__ a2c, float* __restrict__ slots) {
    __shared__ unsigned short tile1[16 * 264];
    __shared__ unsigned short tile2[2][4096];
    __shared__ int sIdx[256], dIdx[256];
    const int tid = threadIdx.x;
    const int w = tid >> 6, lane = tid & 63, quad = lane >> 4, l15 = lane & 15;
    const int perm = l15 * 4 + quad;
    const size_t base = (size_t)blockIdx.x * 256;
    const size_t blk16 = (size_t)blockIdx.x * 16;
    sIdx[tid] = src[base + tid];
    dIdx[tid] = dst[base + tid];
    bf8_t bfr1[4][2];
    float bias4[4];
#pragma unroll
    for (int j = 0; j < 4; ++j) {
        const unsigned short* wp = W1e + (size_t)((w * 4 + j) * 16 + l15) * 64 + quad * 8;
        bfr1[j][0] = *(const bf8_t*)(wp);
        bfr1[j][1] = *(const bf8_t*)(wp + 32);
        bias4[j] = b1p[(w * 4 + j) * 16 + l15];
    }
    bf8_t bfr2[2][8];
    float bias2[2];
#pragma unroll
    for (int j = 0; j < 2; ++j) {
        const unsigned short* wp = W2p + (size_t)((w * 2 + j) * 16 + l15) * 256 + quad * 8;
#pragma unroll
        for (int ks = 0; ks < 8; ++ks) bfr2[j][ks] = *(const bf8_t*)(wp + ks * 32);
        bias2[j] = b2p[(w * 2 + j) * 16 + l15];
    }
    const int erow = tid >> 4, ex = tid & 15;
    float s0 = 0.f, q0 = 0.f, s1 = 0.f, q1 = 0.f;
    __syncthreads();  // publish sIdx/dIdx
    bf8_t af0, af1;
    uint4 gs0, gs1, gd0, gd1;
    {
        const unsigned short* ap = ebf + blk16 * 1024 + perm * 8;
        af0 = *(const bf8_t*)(ap);
        af1 = *(const bf8_t*)(ap + 512);
        const size_t sr = (size_t)sIdx[erow] * 256, dr = (size_t)dIdx[erow] * 256;
        gs0 = *(const uint4*)(Ps + sr + ex * 8);
        gs1 = *(const uint4*)(Ps + sr + ex * 8 + 128);
        gd0 = *(const uint4*)(Pd + dr + ex * 8);
        gd1 = *(const uint4*)(Pd + dr + ex * 8 + 128);
    }
    for (int mc = 0; mc < 16; ++mc) {
        unsigned short* t2 = tile2[mc & 1];
        // GEMM1 -> tile1 (with b1' bias)
#pragma unroll
        for (int j = 0; j < 4; ++j) {
            f4_t t = {0.f, 0.f, 0.f, 0.f};
            t = __builtin_amdgcn_mfma_f32_16x16x32_bf16(af0, bfr1[j][0], t, 0, 0, 0);
            t = __builtin_amdgcn_mfma_f32_16x16x32_bf16(af1, bfr1[j][1], t, 0, 0, 0);
#pragma unroll
            for (int r = 0; r < 4; ++r)
                tile1[(quad * 4 + r) * 264 + (w * 4 + j) * 16 + l15] = f2bf(t[r] + bias4[j]);
        }
        if (mc < 15) {  // prefetch next A-frags
            const unsigned short* ap = ebf + (blk16 + mc + 1) * 1024 + perm * 8;
            af0 = *(const bf8_t*)(ap);
            af1 = *(const bf8_t*)(ap + 512);
        }
        __syncthreads();  // tile1 complete (also: prev combine-readers done)
        // combine -> ReLU'd a1 chunk into A-tiled tile2[buf]
#pragma unroll
        for (int i = 0; i < 2; ++i) {
            uint4 tv = *(const uint4*)(&tile1[erow * 264 + ex * 8 + 128 * i]);
            const unsigned short* tu = (const unsigned short*)&tv;
            const unsigned short* su = (const unsigned short*)(i ? &gs1 : &gs0);
            const unsigned short* du = (const unsigned short*)(i ? &gd1 : &gd0);
            unsigned short ov[8];
#pragma unroll
            for (int j = 0; j < 8; ++j) {
                float v = bf2f(tu[j]) + bf2f(su[j]) + bf2f(du[j]);
                ov[j] = f2bf(fmaxf(v, 0.f));
            }
            *(uint4*)(&t2[((ex >> 2) + 4 * i) * 512 + (erow * 4 + (ex & 3)) * 8]) = *(const uint4*)ov;
        }
        if (mc < 15) {  // prefetch next gathers
            const size_t sr = (size_t)sIdx[(mc + 1) * 16 + erow] * 256;
            const size_t dr = (size_t)dIdx[(mc + 1) * 16 + erow] * 256;
            gs0 = *(const uint4*)(Ps + sr + ex * 8);
            gs1 = *(const uint4*)(Ps + sr + ex * 8 + 128);
            gd0 = *(const uint4*)(Pd + dr + ex * 8);
            gd1 = *(const uint4*)(Pd + dr + ex * 8 + 128);
        }
        __syncthreads();  // tile2[buf] complete
        // GEMM2: A-frags from tile2, W2p in regs
        f4_t acc0 = {0.f, 0.f, 0.f, 0.f}, acc1 = acc0;
#pragma unroll
        for (int ks = 0; ks < 8; ++ks) {
            bf8_t a = *(const bf8_t*)(&t2[ks * 512 + perm * 8]);
            acc0 = __builtin_amdgcn_mfma_f32_16x16x32_bf16(a, bfr2[0][ks], acc0, 0, 0, 0);
            acc1 = __builtin_amdgcn_mfma_f32_16x16x32_bf16(a, bfr2[1][ks], acc1, 0, 0, 0);
        }
        unsigned short* outp = a2c + (blk16 + mc) * 2048;
        unsigned short pv[4];
#pragma unroll
        for (int r = 0; r < 4; ++r) {
            float v = fmaxf(acc0[r] + bias2[0], 0.f);
            pv[r] = f2bf(v); s0 += v; q0 += v * v;
        }
        *(uint2*)(outp + (((w * 2) * 16 + l15) * 4 + quad) * 4) = *(const uint2*)pv;
#pragma unroll
        for (int r = 0; r < 4; ++r) {
            float v = fmaxf(acc1[r] + bias2[1], 0.f);
            pv[r] = f2bf(v); s1 += v; q1 += v * v;
        }
        *(uint2*)(outp + (((w * 2 + 1) * 16 + l15) * 4 + quad) * 4) = *(const uint2*)pv;
    }
    s0 += __shfl_xor(s0, 16); s0 += __shfl_xor(s0, 32);
    q0 += __shfl_xor(q0, 16); q0 += __shfl_xor(q0, 32);
    s1 += __shfl_xor(s1, 16); s1 += __shfl_xor(s1, 32);
    q1 += __shfl_xor(q1, 16); q1 += __shfl_xor(q1, 32);
    if (lane < 16) {
        float* sl = slots + (size_t)(blockIdx.x & 63) * 256;
        const int c0 = (w * 2) * 16 + l15;
        atomicAdd(&sl[c0], s0); atomicAdd(&sl[128 + c0], q0);
        atomicAdd(&sl[c0 + 16], s1); atomicAdd(&sl[128 + c0 + 16], q1);
    }
}

__global__ __launch_bounds__(128) void k_fold2(const float* __restrict__ slots,
        const float* __restrict__ g2, const float* __restrict__ b2n,
        const float* __restrict__ W3, const float* __restrict__ b3,
        float* __restrict__ w3p, float* __restrict__ b3p) {
    __shared__ float red[128];
    const int tid = threadIdx.x;
    float S = 0.f, Q = 0.f;
    for (int s = 0; s < 64; ++s) { S += slots[s * 256 + tid]; Q += slots[s * 256 + 128 + tid]; }
    const float invE = 1.f / (float)N_EDGES;
    float mu = S * invE;
    float var = Q * invE - mu * mu;
    float scl = g2[tid] * rsqrtf(var + 1e-5f);
    float shf = b2n[tid] - mu * scl;
    w3p[tid] = W3[tid] * scl;
    red[tid] = W3[tid] * shf;
    __syncthreads();
    for (int st = 64; st > 0; st >>= 1) {
        if (tid < st) red[tid] += red[tid + st];
        __syncthreads();
    }
    if (tid == 0) b3p[0] = b3[0] + red[0];
}

// out = a2 . w3' + b3' from C-layout cells; wave per 16-row block, shuffle reduce.
__global__ __launch_bounds__(256) void k_L3(const unsigned short* __restrict__ a2c,
        const float* __restrict__ w3p, const float* __restrict__ b3p, float* __restrict__ out) {
    __shared__ float wl[128];
    const int tid = threadIdx.x;
    if (tid < 128) wl[tid] = w3p[tid];
    __syncthreads();
    const int w = tid >> 6, lane = tid & 63, q = lane >> 4, c = lane & 15;
    const float bb = b3p[0];
#pragma unroll
    for (int i = 0; i < 4; ++i) {
        const size_t b = (size_t)blockIdx.x * 16 + w * 4 + i;
        const unsigned short* bp = a2c + b * 2048 + c * 16 + q * 4;
        float a0 = 0.f, a1r = 0.f, a2r = 0.f, a3r = 0.f;
#pragma unroll
        for (int jt = 0; jt < 8; ++jt) {
            uint2 v = *(const uint2*)(bp + jt * 256);
            const unsigned short* u = (const unsigned short*)&v;
            const float wv = wl[jt * 16 + c];
            a0 += bf2f(u[0]) * wv; a1r += bf2f(u[1]) * wv;
            a2r += bf2f(u[2]) * wv; a3r += bf2f(u[3]) * wv;
        }
#pragma unroll
        for (int d = 1; d <= 8; d <<= 1) {
            a0 += __shfl_xor(a0, d); a1r += __shfl_xor(a1r, d);
            a2r += __shfl_xor(a2r, d); a3r += __shfl_xor(a3r, d);
        }
        if (c == 0) {
            f4_t o = {a0 + bb, a1r + bb, a2r + bb, a3r + bb};
            *(f4_t*)(out + b * 16 + q * 4) = o;
        }
    }
}

extern "C" void kernel_launch(void* const* d_in, const int* in_sizes, int n_in,
                              void* d_out, int out_size, void* d_ws, size_t ws_size,
                              hipStream_t stream) {
    (void)in_sizes; (void)n_in; (void)out_size; (void)ws_size;
    const float* h   = (const float*)d_in[0];
    const float* e   = (const float*)d_in[1];
    const int*   src = (const int*)d_in[2];
    const int*   dst = (const int*)d_in[3];
    const float* bn0_g = (const float*)d_in[4];
    const float* bn0_b = (const float*)d_in[5];
    const float* W1 = (const float*)d_in[6];
    const float* b1 = (const float*)d_in[7];
    const float* bn1_g = (const float*)d_in[8];
    const float* bn1_b = (const float*)d_in[9];
    const float* W2 = (const float*)d_in[10];
    const float* b2 = (const float*)d_in[11];
    const float* bn2_g = (const float*)d_in[12];
    const float* bn2_b = (const float*)d_in[13];
    const float* W3 = (const float*)d_in[14];
    const float* b3 = (const float*)d_in[15];

    char* ws = (char*)d_ws;
    size_t off = 0;
    auto alloc = [&](size_t bytes) { char* p = ws + off; off += (bytes + 255) & ~(size_t)255; return p; };
    int*   cnt_s = (int*)alloc((size_t)N_NODES * 4);
    int*   cnt_d = (int*)alloc((size_t)N_NODES * 4);
    float* bn0_sum = (float*)alloc(320 * 4);
    float* bn0_sq  = (float*)alloc(320 * 4);
    float* bn1_slots = (float*)alloc(64 * 512 * 4);
    float* bn2_slots = (float*)alloc(64 * 256 * 4);
    const size_t zero_end = off;
    float* scale0 = (float*)alloc(320 * 4);
    float* shift0 = (float*)alloc(320 * 4);
    unsigned short* W1s = (unsigned short*)alloc(256 * 128 * 2);
    unsigned short* W1d = (unsigned short*)alloc(256 * 128 * 2);
    unsigned short* W1e = (unsigned short*)alloc(256 * 64 * 2);
    float* b1p = (float*)alloc(256 * 4);
    unsigned short* W2p = (unsigned short*)alloc(128 * 256 * 2);
    float* b2p = (float*)alloc(128 * 4);
    float* w3p = (float*)alloc(128 * 4);
    float* b3p = (float*)alloc(4);
    unsigned short* Ps = (unsigned short*)alloc((size_t)N_NODES * 256 * 2);
    unsigned short* Pd = (unsigned short*)alloc((size_t)N_NODES * 256 * 2);
    unsigned short* ebf = (unsigned short*)alloc((size_t)(N_EDGES / 16) * 2048); // 102.4 MB
    unsigned short* a2c = (unsigned short*)alloc((size_t)(N_EDGES / 16) * 4096); // 204.8 MB

    hipMemsetAsync(d_ws, 0, zero_end, stream);
    k_hist<<<(N_EDGES + 255) / 256, 256, 0, stream>>>(src, dst, cnt_s, cnt_d);
    k_ecvt<<<256, 256, 0, stream>>>(e, ebf, bn0_sum, bn0_sq);
    k_hstats<<<200, 256, 0, stream>>>(h, cnt_s, cnt_d, bn0_sum, bn0_sq);
    k_fold0<<<1, 320, 0, stream>>>(bn0_sum, bn0_sq, bn0_g, bn0_b, scale0, shift0);
    k_foldW1<<<1, 320, 0, stream>>>(W1, b1, scale0, shift0, W1s, W1d, W1e, b1p);
    k_P<<<dim3(196, 2), 256, 0, stream>>>(h, W1s, W1d, Ps, Pd);
    k_stats1<<<N_EDGES / 256, 256, 0, stream>>>(ebf, src, dst, Ps, Pd, W1e, b1p, bn1_slots);
    k_fold1<<<1, 256, 0, stream>>>(bn1_slots, bn1_g, bn1_b, W2, b2, W2p, b2p);
    k_L12<<<N_EDGES / 256, 256, 0, stream>>>(ebf, src, dst, Ps, Pd, W1e, b1p, W2p, b2p, a2c, bn2_slots);
    k_fold2<<<1, 128, 0, stream>>>(bn2_slots, bn2_g, bn2_b, W3, b3, w3p, b3p);
    k_L3<<<N_EDGES / 256, 256, 0, stream>>>(a2c, w3p, b3p, (float*)d_out);
}

// Round 9
// 1050.580 us; speedup vs baseline: 1.4318x; 1.0004x over previous
//
#include <hip/hip_runtime.h>

// NNPredictor: edge MLP with BN folded into weights.
// R9 = R8 with compile fix: __builtin_nontemporal_* requires real vector types,
// not HIP_vector_type structs -> use ext_vector_type aliases u2_t/u4_t.
// Non-temporal hints on streaming tensors (e, ebf, a2c) keep the 102 MB Ps/Pd
// gather working set resident in the 256 MB L3.

#define N_EDGES 800000
#define N_NODES 50000

typedef __attribute__((ext_vector_type(8))) short bf8_t;
typedef __attribute__((ext_vector_type(4))) float f4_t;
typedef __attribute__((ext_vector_type(2))) unsigned int u2_t;
typedef __attribute__((ext_vector_type(4))) unsigned int u4_t;

__device__ __forceinline__ unsigned short f2bf(float f) {
    unsigned int u = __builtin_bit_cast(unsigned int, f);
    u += 0x7FFFu + ((u >> 16) & 1u);
    return (unsigned short)(u >> 16);
}
__device__ __forceinline__ float bf2f(unsigned short s) {
    unsigned int u = ((unsigned int)s) << 16;
    return __builtin_bit_cast(float, u);
}
__device__ __forceinline__ bf8_t cvt8(f4_t x, f4_t y) {
    bf8_t r;
    r[0] = (short)f2bf(x[0]); r[1] = (short)f2bf(x[1]);
    r[2] = (short)f2bf(x[2]); r[3] = (short)f2bf(x[3]);
    r[4] = (short)f2bf(y[0]); r[5] = (short)f2bf(y[1]);
    r[6] = (short)f2bf(y[2]); r[7] = (short)f2bf(y[3]);
    return r;
}

__global__ __launch_bounds__(256) void k_hist(const int* __restrict__ src, const int* __restrict__ dst,
                                              int* __restrict__ cs, int* __restrict__ cd) {
    int i = blockIdx.x * 256 + threadIdx.x;
    if (i < N_EDGES) {
        atomicAdd(&cs[src[i]], 1);
        atomicAdd(&cd[dst[i]], 1);
    }
}

// e -> bf16 in A-tiled layout [blk16][ks(2)][(row*4+colgrp)][8], fused BN0 e-col stats.
__global__ __launch_bounds__(256) void k_ecvt(const float* __restrict__ e,
        unsigned short* __restrict__ ebf, float* __restrict__ sum, float* __restrict__ sq) {
    const int tid = threadIdx.x;
    const int lane = tid & 63;
    const int cg = tid & 7, rr = tid >> 3;
    f4_t sa = {0.f,0.f,0.f,0.f}, sb = sa, qa = sa, qb = sa;
    for (int r = blockIdx.x * 32 + rr; r < N_EDGES; r += gridDim.x * 32) {
        f4_t va = __builtin_nontemporal_load((const f4_t*)(e + (size_t)r * 64 + cg * 8));
        f4_t vb = __builtin_nontemporal_load((const f4_t*)(e + (size_t)r * 64 + cg * 8 + 4));
        sa += va; qa += va * va; sb += vb; qb += vb * vb;
        bf8_t o = cvt8(va, vb);
        __builtin_nontemporal_store(o,
            (bf8_t*)(ebf + (size_t)(r >> 4) * 1024 + (cg >> 2) * 512 + (((r & 15) << 2) + (cg & 3)) * 8));
    }
#pragma unroll
    for (int d = 8; d <= 32; d <<= 1) {
#pragma unroll
        for (int j = 0; j < 4; ++j) {
            sa[j] += __shfl_xor(sa[j], d); qa[j] += __shfl_xor(qa[j], d);
            sb[j] += __shfl_xor(sb[j], d); qb[j] += __shfl_xor(qb[j], d);
        }
    }
    __shared__ float red[128];
    if (tid < 128) red[tid] = 0.f;
    __syncthreads();
    if (lane < 8) {
#pragma unroll
        for (int j = 0; j < 4; ++j) {
            atomicAdd(&red[lane * 8 + j], sa[j]);
            atomicAdd(&red[lane * 8 + 4 + j], sb[j]);
            atomicAdd(&red[64 + lane * 8 + j], qa[j]);
            atomicAdd(&red[64 + lane * 8 + 4 + j], qb[j]);
        }
    }
    __syncthreads();
    if (tid < 64) atomicAdd(&sum[256 + tid], red[tid]);
    else if (tid < 128) atomicAdd(&sq[256 + tid - 64], red[tid]);
}

__global__ __launch_bounds__(256) void k_hstats(const float* __restrict__ h,
                                                const int* __restrict__ cs, const int* __restrict__ cd,
                                                float* __restrict__ sum, float* __restrict__ sq) {
    const int tid = threadIdx.x;
    const int c = tid & 127, g = tid >> 7;
    float ss = 0.f, qs = 0.f, sd = 0.f, qd = 0.f;
    for (int n = blockIdx.x * 2 + g; n < N_NODES; n += gridDim.x * 2) {
        float v = h[(size_t)n * 128 + c];
        float a = (float)cs[n], b = (float)cd[n];
        ss += a * v; qs += a * v * v;
        sd += b * v; qd += b * v * v;
    }
    __shared__ float red[256];
    red[tid] = ss; __syncthreads();
    if (tid < 128) atomicAdd(&sum[tid], red[tid] + red[tid + 128]);
    __syncthreads();
    red[tid] = qs; __syncthreads();
    if (tid < 128) atomicAdd(&sq[tid], red[tid] + red[tid + 128]);
    __syncthreads();
    red[tid] = sd; __syncthreads();
    if (tid < 128) atomicAdd(&sum[128 + tid], red[tid] + red[tid + 128]);
    __syncthreads();
    red[tid] = qd; __syncthreads();
    if (tid < 128) atomicAdd(&sq[128 + tid], red[tid] + red[tid + 128]);
}

__global__ __launch_bounds__(320) void k_fold0(const float* __restrict__ sum, const float* __restrict__ sq,
        const float* __restrict__ g0, const float* __restrict__ b0,
        float* __restrict__ scale0, float* __restrict__ shift0) {
    int j = threadIdx.x;
    if (j < 320) {
        const float invE = 1.f / (float)N_EDGES;
        float mu = sum[j] * invE;
        float var = sq[j] * invE - mu * mu;
        float sc = g0[j] * rsqrtf(var + 1e-5f);
        scale0[j] = sc;
        shift0[j] = b0[j] - mu * sc;
    }
}

__global__ __launch_bounds__(320) void k_foldW1(const float* __restrict__ W1, const float* __restrict__ b1,
        const float* __restrict__ scale0, const float* __restrict__ shift0,
        unsigned short* __restrict__ W1s, unsigned short* __restrict__ W1d,
        unsigned short* __restrict__ W1e, float* __restrict__ b1p) {
    __shared__ float sc[320], sh[320];
    const int tid = threadIdx.x;
    if (tid < 320) { sc[tid] = scale0[tid]; sh[tid] = shift0[tid]; }
    __syncthreads();
    if (tid < 256) {
        float acc = b1[tid];
        const float* wr = W1 + (size_t)tid * 320;
        for (int j = 0; j < 320; ++j) {
            float wv = wr[j];
            acc += wv * sh[j];
            unsigned short wb = f2bf(wv * sc[j]);
            if (j < 128) W1s[tid * 128 + j] = wb;
            else if (j < 256) W1d[tid * 128 + (j - 128)] = wb;
            else W1e[tid * 64 + (j - 256)] = wb;
        }
        b1p[tid] = acc;
    }
}

// P = h @ W'^T : M=50000 (256/block), N=256, K=128. Row-major bf16 output.
__global__ __launch_bounds__(256) void k_P(const float* __restrict__ h,
        const unsigned short* __restrict__ W1s, const unsigned short* __restrict__ W1d,
        unsigned short* __restrict__ Ps, unsigned short* __restrict__ Pd) {
    __shared__ unsigned short tile[16 * 264];
    const int tid = threadIdx.x;
    const int w = tid >> 6, lane = tid & 63, quad = lane >> 4, l15 = lane & 15;
    const unsigned short* W = blockIdx.y ? W1d : W1s;
    unsigned short* P = blockIdx.y ? Pd : Ps;
    const size_t base = (size_t)blockIdx.x * 256;
    bf8_t bfr[4][4];
#pragma unroll
    for (int j = 0; j < 4; ++j) {
        const unsigned short* wp = W + (size_t)((w * 4 + j) * 16 + l15) * 128 + quad * 8;
#pragma unroll
        for (int ks = 0; ks < 4; ++ks) bfr[j][ks] = *(const bf8_t*)(wp + ks * 32);
    }
    const int erow = tid >> 4, ex = tid & 15;
    for (int mc = 0; mc < 16; ++mc) {
        const size_t row0 = base + mc * 16;
        size_t ar = row0 + l15; if (ar >= N_NODES) ar = N_NODES - 1;
        const float* hp = h + ar * 128 + quad * 8;
        bf8_t af[4];
#pragma unroll
        for (int ks = 0; ks < 4; ++ks)
            af[ks] = cvt8(*(const f4_t*)(hp + ks * 32), *(const f4_t*)(hp + ks * 32 + 4));
#pragma unroll
        for (int j = 0; j < 4; ++j) {
            f4_t t = {0.f, 0.f, 0.f, 0.f};
#pragma unroll
            for (int ks = 0; ks < 4; ++ks)
                t = __builtin_amdgcn_mfma_f32_16x16x32_bf16(af[ks], bfr[j][ks], t, 0, 0, 0);
#pragma unroll
            for (int r = 0; r < 4; ++r)
                tile[(quad * 4 + r) * 264 + (w * 4 + j) * 16 + l15] = f2bf(t[r]);
        }
        __syncthreads();
        const size_t orow = row0 + erow;
        if (orow < N_NODES) {
            u4_t v0 = *(const u4_t*)(tile + erow * 264 + ex * 16);
            u4_t v1 = *(const u4_t*)(tile + erow * 264 + ex * 16 + 8);
            *(u4_t*)(P + orow * 256 + ex * 16) = v0;
            *(u4_t*)(P + orow * 256 + ex * 16 + 8) = v1;
        }
        __syncthreads();
    }
}

// Pass A: BN1 stats only, no stores. GEMM1 accs stay in C-layout registers;
// gathers are scalar u16 (cached); ebf read is non-temporal streaming.
__global__ __launch_bounds__(256) void k_stats1(const unsigned short* __restrict__ ebf,
        const int* __restrict__ src, const int* __restrict__ dst,
        const unsigned short* __restrict__ Ps, const unsigned short* __restrict__ Pd,
        const unsigned short* __restrict__ W1e, const float* __restrict__ b1p,
        float* __restrict__ slots) {
    __shared__ int sIdx[256], dIdx[256];
    const int tid = threadIdx.x;
    const int w = tid >> 6, lane = tid & 63, quad = lane >> 4, l15 = lane & 15;
    const int perm = l15 * 4 + quad;
    const size_t base = (size_t)blockIdx.x * 256;
    const size_t blk16 = (size_t)blockIdx.x * 16;
    sIdx[tid] = src[base + tid];
    dIdx[tid] = dst[base + tid];
    bf8_t bfr[4][2];
    float bias4[4];
#pragma unroll
    for (int j = 0; j < 4; ++j) {
        const unsigned short* wp = W1e + (size_t)((w * 4 + j) * 16 + l15) * 64 + quad * 8;
        bfr[j][0] = *(const bf8_t*)(wp);
        bfr[j][1] = *(const bf8_t*)(wp + 32);
        bias4[j] = b1p[(w * 4 + j) * 16 + l15];
    }
    const int cb = w * 64 + l15;
    float s[4] = {0.f, 0.f, 0.f, 0.f}, q[4] = {0.f, 0.f, 0.f, 0.f};
    __syncthreads();  // publish sIdx/dIdx
    bf8_t af0, af1;
    {
        const unsigned short* ap = ebf + blk16 * 1024 + perm * 8;
        af0 = __builtin_nontemporal_load((const bf8_t*)(ap));
        af1 = __builtin_nontemporal_load((const bf8_t*)(ap + 512));
    }
    for (int mc = 0; mc < 16; ++mc) {
        const int r0 = mc * 16 + quad * 4;
        const unsigned short* p0 = Ps + (size_t)sIdx[r0 + 0] * 256 + cb;
        const unsigned short* p1 = Ps + (size_t)sIdx[r0 + 1] * 256 + cb;
        const unsigned short* p2 = Ps + (size_t)sIdx[r0 + 2] * 256 + cb;
        const unsigned short* p3 = Ps + (size_t)sIdx[r0 + 3] * 256 + cb;
        const unsigned short* d0 = Pd + (size_t)dIdx[r0 + 0] * 256 + cb;
        const unsigned short* d1 = Pd + (size_t)dIdx[r0 + 1] * 256 + cb;
        const unsigned short* d2 = Pd + (size_t)dIdx[r0 + 2] * 256 + cb;
        const unsigned short* d3 = Pd + (size_t)dIdx[r0 + 3] * 256 + cb;
        unsigned short ps[4][4], pd[4][4];
#pragma unroll
        for (int j = 0; j < 4; ++j) {
            ps[0][j] = p0[j * 16]; ps[1][j] = p1[j * 16];
            ps[2][j] = p2[j * 16]; ps[3][j] = p3[j * 16];
            pd[0][j] = d0[j * 16]; pd[1][j] = d1[j * 16];
            pd[2][j] = d2[j * 16]; pd[3][j] = d3[j * 16];
        }
        f4_t acc[4];
#pragma unroll
        for (int j = 0; j < 4; ++j) {
            f4_t t = {0.f, 0.f, 0.f, 0.f};
            t = __builtin_amdgcn_mfma_f32_16x16x32_bf16(af0, bfr[j][0], t, 0, 0, 0);
            acc[j] = __builtin_amdgcn_mfma_f32_16x16x32_bf16(af1, bfr[j][1], t, 0, 0, 0);
        }
        if (mc < 15) {
            const unsigned short* ap = ebf + (blk16 + mc + 1) * 1024 + perm * 8;
            af0 = __builtin_nontemporal_load((const bf8_t*)(ap));
            af1 = __builtin_nontemporal_load((const bf8_t*)(ap + 512));
        }
#pragma unroll
        for (int j = 0; j < 4; ++j)
#pragma unroll
            for (int r = 0; r < 4; ++r) {
                float v = acc[j][r] + bf2f(ps[r][j]) + bf2f(pd[r][j]) + bias4[j];
                v = fmaxf(v, 0.f);
                s[j] += v; q[j] += v * v;
            }
    }
#pragma unroll
    for (int j = 0; j < 4; ++j) {
        s[j] += __shfl_xor(s[j], 16); s[j] += __shfl_xor(s[j], 32);
        q[j] += __shfl_xor(q[j], 16); q[j] += __shfl_xor(q[j], 32);
    }
    if (lane < 16) {
        float* sl = slots + (size_t)(blockIdx.x & 63) * 512;
#pragma unroll
        for (int j = 0; j < 4; ++j) {
            atomicAdd(&sl[cb + j * 16], s[j]);
            atomicAdd(&sl[256 + cb + j * 16], q[j]);
        }
    }
}

__global__ __launch_bounds__(256) void k_fold1(const float* __restrict__ slots,
        const float* __restrict__ g1, const float* __restrict__ b1n,
        const float* __restrict__ W2, const float* __restrict__ b2,
        unsigned short* __restrict__ W2p, float* __restrict__ b2p) {
    __shared__ float sc[256], sh[256];
    const int tid = threadIdx.x;
    float S = 0.f, Q = 0.f;
    for (int s = 0; s < 64; ++s) { S += slots[s * 512 + tid]; Q += slots[s * 512 + 256 + tid]; }
    const float invE = 1.f / (float)N_EDGES;
    float mu = S * invE;
    float var = Q * invE - mu * mu;
    float scl = g1[tid] * rsqrtf(var + 1e-5f);
    sc[tid] = scl; sh[tid] = b1n[tid] - mu * scl;
    __syncthreads();
    if (tid < 128) {
        float acc = b2[tid];
        const float* wr = W2 + (size_t)tid * 256;
        for (int j = 0; j < 256; ++j) {
            float wv = wr[j];
            acc += wv * sh[j];
            W2p[tid * 256 + j] = f2bf(wv * sc[j]);
        }
        b2p[tid] = acc;
    }
}

// Pass B: recompute a1 chunk (GEMM1 -> tile1 -> combine) into A-tiled LDS
// (double-buffered tile2), then GEMM2 (W2p in regs) -> a2 C-cells + BN2 stats.
__global__ __launch_bounds__(256) void k_L12(const unsigned short* __restrict__ ebf,
        const int* __restrict__ src, const int* __restrict__ dst,
        const unsigned short* __restrict__ Ps, const unsigned short* __restrict__ Pd,
        const unsigned short* __restrict__ W1e, const float* __restrict__ b1p,
        const unsigned short* __restrict__ W2p, const float* __restrict__ b2p,
        unsigned short* __restrict__ a2c, float* __restrict__ slots) {
    __shared__ unsigned short tile1[16 * 264];
    __shared__ unsigned short tile2[2][4096];
    __shared__ int sIdx[256], dIdx[256];
    const int tid = threadIdx.x;
    const int w = tid >> 6, lane = tid & 63, quad = lane >> 4, l15 = lane & 15;
    const int perm = l15 * 4 + quad;
    const size_t base = (size_t)blockIdx.x * 256;
    const size_t blk16 = (size_t)blockIdx.x * 16;
    sIdx[tid] = src[base + tid];
    dIdx[tid] = dst[base + tid];
    bf8_t bfr1[4][2];
    float bias4[4];
#pragma unroll
    for (int j = 0; j < 4; ++j) {
        const unsigned short* wp = W1e + (size_t)((w * 4 + j) * 16 + l15) * 64 + quad * 8;
        bfr1[j][0] = *(const bf8_t*)(wp);
        bfr1[j][1] = *(const bf8_t*)(wp + 32);
        bias4[j] = b1p[(w * 4 + j) * 16 + l15];
    }
    bf8_t bfr2[2][8];
    float bias2[2];
#pragma unroll
    for (int j = 0; j < 2; ++j) {
        const unsigned short* wp = W2p + (size_t)((w * 2 + j) * 16 + l15) * 256 + quad * 8;
#pragma unroll
        for (int ks = 0; ks < 8; ++ks) bfr2[j][ks] = *(const bf8_t*)(wp + ks * 32);
        bias2[j] = b2p[(w * 2 + j) * 16 + l15];
    }
    const int erow = tid >> 4, ex = tid & 15;
    float s0 = 0.f, q0 = 0.f, s1 = 0.f, q1 = 0.f;
    __syncthreads();  // publish sIdx/dIdx
    bf8_t af0, af1;
    u4_t gs0, gs1, gd0, gd1;
    {
        const unsigned short* ap = ebf + blk16 * 1024 + perm * 8;
        af0 = __builtin_nontemporal_load((const bf8_t*)(ap));
        af1 = __builtin_nontemporal_load((const bf8_t*)(ap + 512));
        const size_t sr = (size_t)sIdx[erow] * 256, dr = (size_t)dIdx[erow] * 256;
        gs0 = *(const u4_t*)(Ps + sr + ex * 8);
        gs1 = *(const u4_t*)(Ps + sr + ex * 8 + 128);
        gd0 = *(const u4_t*)(Pd + dr + ex * 8);
        gd1 = *(const u4_t*)(Pd + dr + ex * 8 + 128);
    }
    for (int mc = 0; mc < 16; ++mc) {
        unsigned short* t2 = tile2[mc & 1];
#pragma unroll
        for (int j = 0; j < 4; ++j) {
            f4_t t = {0.f, 0.f, 0.f, 0.f};
            t = __builtin_amdgcn_mfma_f32_16x16x32_bf16(af0, bfr1[j][0], t, 0, 0, 0);
            t = __builtin_amdgcn_mfma_f32_16x16x32_bf16(af1, bfr1[j][1], t, 0, 0, 0);
#pragma unroll
            for (int r = 0; r < 4; ++r)
                tile1[(quad * 4 + r) * 264 + (w * 4 + j) * 16 + l15] = f2bf(t[r] + bias4[j]);
        }
        if (mc < 15) {
            const unsigned short* ap = ebf + (blk16 + mc + 1) * 1024 + perm * 8;
            af0 = __builtin_nontemporal_load((const bf8_t*)(ap));
            af1 = __builtin_nontemporal_load((const bf8_t*)(ap + 512));
        }
        __syncthreads();  // tile1 complete (also: prev combine-readers done)
#pragma unroll
        for (int i = 0; i < 2; ++i) {
            u4_t tv = *(const u4_t*)(&tile1[erow * 264 + ex * 8 + 128 * i]);
            const unsigned short* tu = (const unsigned short*)&tv;
            const unsigned short* su = (const unsigned short*)(i ? &gs1 : &gs0);
            const unsigned short* du = (const unsigned short*)(i ? &gd1 : &gd0);
            unsigned short ov[8];
#pragma unroll
            for (int j = 0; j < 8; ++j) {
                float v = bf2f(tu[j]) + bf2f(su[j]) + bf2f(du[j]);
                ov[j] = f2bf(fmaxf(v, 0.f));
            }
            *(u4_t*)(&t2[((ex >> 2) + 4 * i) * 512 + (erow * 4 + (ex & 3)) * 8]) = *(const u4_t*)ov;
        }
        if (mc < 15) {
            const size_t sr = (size_t)sIdx[(mc + 1) * 16 + erow] * 256;
            const size_t dr = (size_t)dIdx[(mc + 1) * 16 + erow] * 256;
            gs0 = *(const u4_t*)(Ps + sr + ex * 8);
            gs1 = *(const u4_t*)(Ps + sr + ex * 8 + 128);
            gd0 = *(const u4_t*)(Pd + dr + ex * 8);
            gd1 = *(const u4_t*)(Pd + dr + ex * 8 + 128);
        }
        __syncthreads();  // tile2[buf] complete
        f4_t acc0 = {0.f, 0.f, 0.f, 0.f}, acc1 = acc0;
#pragma unroll
        for (int ks = 0; ks < 8; ++ks) {
            bf8_t a = *(const bf8_t*)(&t2[ks * 512 + perm * 8]);
            acc0 = __builtin_amdgcn_mfma_f32_16x16x32_bf16(a, bfr2[0][ks], acc0, 0, 0, 0);
            acc1 = __builtin_amdgcn_mfma_f32_16x16x32_bf16(a, bfr2[1][ks], acc1, 0, 0, 0);
        }
        unsigned short* outp = a2c + (blk16 + mc) * 2048;
        unsigned short pv[4];
#pragma unroll
        for (int r = 0; r < 4; ++r) {
            float v = fmaxf(acc0[r] + bias2[0], 0.f);
            pv[r] = f2bf(v); s0 += v; q0 += v * v;
        }
        __builtin_nontemporal_store(*(const u2_t*)pv,
            (u2_t*)(outp + (((w * 2) * 16 + l15) * 4 + quad) * 4));
#pragma unroll
        for (int r = 0; r < 4; ++r) {
            float v = fmaxf(acc1[r] + bias2[1], 0.f);
            pv[r] = f2bf(v); s1 += v; q1 += v * v;
        }
        __builtin_nontemporal_store(*(const u2_t*)pv,
            (u2_t*)(outp + (((w * 2 + 1) * 16 + l15) * 4 + quad) * 4));
    }
    s0 += __shfl_xor(s0, 16); s0 += __shfl_xor(s0, 32);
    q0 += __shfl_xor(q0, 16); q0 += __shfl_xor(q0, 32);
    s1 += __shfl_xor(s1, 16); s1 += __shfl_xor(s1, 32);
    q1 += __shfl_xor(q1, 16); q1 += __shfl_xor(q1, 32);
    if (lane < 16) {
        float* sl = slots + (size_t)(blockIdx.x & 63) * 256;
        const int c0 = (w * 2) * 16 + l15;
        atomicAdd(&sl[c0], s0); atomicAdd(&sl[128 + c0], q0);
        atomicAdd(&sl[c0 + 16], s1); atomicAdd(&sl[128 + c0 + 16], q1);
    }
}

__global__ __launch_bounds__(128) void k_fold2(const float* __restrict__ slots,
        const float* __restrict__ g2, const float* __restrict__ b2n,
        const float* __restrict__ W3, const float* __restrict__ b3,
        float* __restrict__ w3p, float* __restrict__ b3p) {
    __shared__ float red[128];
    const int tid = threadIdx.x;
    float S = 0.f, Q = 0.f;
    for (int s = 0; s < 64; ++s) { S += slots[s * 256 + tid]; Q += slots[s * 256 + 128 + tid]; }
    const float invE = 1.f / (float)N_EDGES;
    float mu = S * invE;
    float var = Q * invE - mu * mu;
    float scl = g2[tid] * rsqrtf(var + 1e-5f);
    float shf = b2n[tid] - mu * scl;
    w3p[tid] = W3[tid] * scl;
    red[tid] = W3[tid] * shf;
    __syncthreads();
    for (int st = 64; st > 0; st >>= 1) {
        if (tid < st) red[tid] += red[tid + st];
        __syncthreads();
    }
    if (tid == 0) b3p[0] = b3[0] + red[0];
}

// out = a2 . w3' + b3' from C-layout cells; wave per 16-row block, shuffle reduce.
__global__ __launch_bounds__(256) void k_L3(const unsigned short* __restrict__ a2c,
        const float* __restrict__ w3p, const float* __restrict__ b3p, float* __restrict__ out) {
    __shared__ float wl[128];
    const int tid = threadIdx.x;
    if (tid < 128) wl[tid] = w3p[tid];
    __syncthreads();
    const int w = tid >> 6, lane = tid & 63, q = lane >> 4, c = lane & 15;
    const float bb = b3p[0];
#pragma unroll
    for (int i = 0; i < 4; ++i) {
        const size_t b = (size_t)blockIdx.x * 16 + w * 4 + i;
        const unsigned short* bp = a2c + b * 2048 + c * 16 + q * 4;
        float a0 = 0.f, a1r = 0.f, a2r = 0.f, a3r = 0.f;
#pragma unroll
        for (int jt = 0; jt < 8; ++jt) {
            u2_t v = __builtin_nontemporal_load((const u2_t*)(bp + jt * 256));
            const unsigned short* u = (const unsigned short*)&v;
            const float wv = wl[jt * 16 + c];
            a0 += bf2f(u[0]) * wv; a1r += bf2f(u[1]) * wv;
            a2r += bf2f(u[2]) * wv; a3r += bf2f(u[3]) * wv;
        }
#pragma unroll
        for (int d = 1; d <= 8; d <<= 1) {
            a0 += __shfl_xor(a0, d); a1r += __shfl_xor(a1r, d);
            a2r += __shfl_xor(a2r, d); a3r += __shfl_xor(a3r, d);
        }
        if (c == 0) {
            f4_t o = {a0 + bb, a1r + bb, a2r + bb, a3r + bb};
            *(f4_t*)(out + b * 16 + q * 4) = o;
        }
    }
}

extern "C" void kernel_launch(void* const* d_in, const int* in_sizes, int n_in,
                              void* d_out, int out_size, void* d_ws, size_t ws_size,
                              hipStream_t stream) {
    (void)in_sizes; (void)n_in; (void)out_size; (void)ws_size;
    const float* h   = (const float*)d_in[0];
    const float* e   = (const float*)d_in[1];
    const int*   src = (const int*)d_in[2];
    const int*   dst = (const int*)d_in[3];
    const float* bn0_g = (const float*)d_in[4];
    const float* bn0_b = (const float*)d_in[5];
    const float* W1 = (const float*)d_in[6];
    const float* b1 = (const float*)d_in[7];
    const float* bn1_g = (const float*)d_in[8];
    const float* bn1_b = (const float*)d_in[9];
    const float* W2 = (const float*)d_in[10];
    const float* b2 = (const float*)d_in[11];
    const float* bn2_g = (const float*)d_in[12];
    const float* bn2_b = (const float*)d_in[13];
    const float* W3 = (const float*)d_in[14];
    const float* b3 = (const float*)d_in[15];

    char* ws = (char*)d_ws;
    size_t off = 0;
    auto alloc = [&](size_t bytes) { char* p = ws + off; off += (bytes + 255) & ~(size_t)255; return p; };
    int*   cnt_s = (int*)alloc((size_t)N_NODES * 4);
    int*   cnt_d = (int*)alloc((size_t)N_NODES * 4);
    float* bn0_sum = (float*)alloc(320 * 4);
    float* bn0_sq  = (float*)alloc(320 * 4);
    float* bn1_slots = (float*)alloc(64 * 512 * 4);
    float* bn2_slots = (float*)alloc(64 * 256 * 4);
    const size_t zero_end = off;
    float* scale0 = (float*)alloc(320 * 4);
    float* shift0 = (float*)alloc(320 * 4);
    unsigned short* W1s = (unsigned short*)alloc(256 * 128 * 2);
    unsigned short* W1d = (unsigned short*)alloc(256 * 128 * 2);
    unsigned short* W1e = (unsigned short*)alloc(256 * 64 * 2);
    float* b1p = (float*)alloc(256 * 4);
    unsigned short* W2p = (unsigned short*)alloc(128 * 256 * 2);
    float* b2p = (float*)alloc(128 * 4);
    float* w3p = (float*)alloc(128 * 4);
    float* b3p = (float*)alloc(4);
    unsigned short* Ps = (unsigned short*)alloc((size_t)N_NODES * 256 * 2);
    unsigned short* Pd = (unsigned short*)alloc((size_t)N_NODES * 256 * 2);
    unsigned short* ebf = (unsigned short*)alloc((size_t)(N_EDGES / 16) * 2048); // 102.4 MB
    unsigned short* a2c = (unsigned short*)alloc((size_t)(N_EDGES / 16) * 4096); // 204.8 MB

    hipMemsetAsync(d_ws, 0, zero_end, stream);
    k_hist<<<(N_EDGES + 255) / 256, 256, 0, stream>>>(src, dst, cnt_s, cnt_d);
    k_ecvt<<<512, 256, 0, stream>>>(e, ebf, bn0_sum, bn0_sq);
    k_hstats<<<200, 256, 0, stream>>>(h, cnt_s, cnt_d, bn0_sum, bn0_sq);
    k_fold0<<<1, 320, 0, stream>>>(bn0_sum, bn0_sq, bn0_g, bn0_b, scale0, shift0);
    k_foldW1<<<1, 320, 0, stream>>>(W1, b1, scale0, shift0, W1s, W1d, W1e, b1p);
    k_P<<<dim3(196, 2), 256, 0, stream>>>(h, W1s, W1d, Ps, Pd);
    k_stats1<<<N_EDGES / 256, 256, 0, stream>>>(ebf, src, dst, Ps, Pd, W1e, b1p, bn1_slots);
    k_fold1<<<1, 256, 0, stream>>>(bn1_slots, bn1_g, bn1_b, W2, b2, W2p, b2p);
    k_L12<<<N_EDGES / 256, 256, 0, stream>>>(ebf, src, dst, Ps, Pd, W1e, b1p, W2p, b2p, a2c, bn2_slots);
    k_fold2<<<1, 128, 0, stream>>>(bn2_slots, bn2_g, bn2_b, W3, b3, w3p, b3p);
    k_L3<<<N_EDGES / 256, 256, 0, stream>>>(a2c, w3p, b3p, (float*)d_out);
}